// Round 6
// baseline (547.769 us; speedup 1.0000x reference)
//
#include <hip/hip_runtime.h>

#define N_NODES 50000
#define N_EDGES 800000
#define LRELU_SLOPE 0.2f
#define BN_EPS 1e-5f

#define BSHIFT 7
#define NBUCK 391            // ceil(50000/128)
#define BCAP 4096            // mean 2048/bucket; overflow falls back (correct for any dist)
#define EPB 4096             // edges per k_bin block
#define NBLKBIN ((N_EDGES + EPB - 1)/EPB)

typedef unsigned int u32;
typedef unsigned long long u64;

__device__ __forceinline__ float lrelu(float x){ return fmaxf(x,0.f) + LRELU_SLOPE*fminf(x,0.f); }
__device__ __forceinline__ float bflo(u32 u){ return __uint_as_float(u<<16); }
__device__ __forceinline__ float bfhi(u32 u){ return __uint_as_float(u & 0xffff0000u); }
__device__ __forceinline__ u32 packbf(float a, float b){
  u32 ua = __float_as_uint(a); ua = (ua + 0x7fffu + ((ua>>16)&1u)) >> 16;
  u32 ub = __float_as_uint(b); ub = (ub + 0x7fffu + ((ub>>16)&1u)) >> 16;
  return ua | (ub<<16);
}

// fp16 pair in a u32 -- no hip_fp16.h API (header lacks __hmax2 on this ROCm).
typedef _Float16 h2v __attribute__((ext_vector_type(2)));
union uhcv { u32 i; h2v h; };
__device__ __forceinline__ u32 packh(float a, float b){
  uhcv c; c.h.x = (_Float16)a; c.h.y = (_Float16)b; return c.i;
}
__device__ __forceinline__ float hlo(u32 u){ uhcv c; c.i = u; return (float)c.h.x; }
__device__ __forceinline__ float hhi(u32 u){ uhcv c; c.i = u; return (float)c.h.y; }
__device__ __forceinline__ h2v toh2(u32 u){ uhcv c; c.i = u; return c.h; }
// packed fp16 ops via asm (VOP3P, baseline gfx9+)
__device__ __forceinline__ u32 pkadd(u32 a, u32 b){
  u32 r; asm("v_pk_add_f16 %0, %1, %2" : "=v"(r) : "v"(a), "v"(b)); return r;
}
__device__ __forceinline__ u32 pkmax0(u32 a){
  u32 r; asm("v_pk_max_f16 %0, %1, %2" : "=v"(r) : "v"(a), "v"(0u)); return r;
}
__device__ __forceinline__ float dot2(u32 a, u32 b, float c){
#if defined(__has_builtin) && __has_builtin(__builtin_amdgcn_fdot2)
  return __builtin_amdgcn_fdot2(toh2(a), toh2(b), c, false);
#else
  float r; asm("v_dot2_f32_f16 %0, %1, %2, %3" : "=v"(r) : "v"(a), "v"(b), "v"(c)); return r;
#endif
}

// packed (cnt<<40 | deg in 2^-26 fixed point)
__device__ __forceinline__ float degof(u64 p){
  return (float)(p & 0xFFFFFFFFFFull) * (1.0f/67108864.0f);
}

// DPP-fused adds: VALU-only lane reduction (no ds_swizzle).
template<int CTRL>
__device__ __forceinline__ float dppadd(float x){
  int y = __builtin_amdgcn_update_dpp(0, __float_as_int(x), CTRL, 0xF, 0xF, false);
  return x + __int_as_float(y);
}
// sum over 8-lane group (lanes differing in bits 0..2)
__device__ __forceinline__ float red8(float p){
  p = dppadd<0x141>(p);  // row_half_mirror: reverse within 8
  p = dppadd<0x4E>(p);   // quad_perm [2,3,0,1] = xor2
  p = dppadd<0xB1>(p);   // quad_perm [1,0,3,2] = xor1
  return p;
}
// sum across the 8 groups (lane bits 3,4,5), keeping l8 lanes separate
__device__ __forceinline__ float redall(float v){
  v = dppadd<0x128>(v);          // row_ror:8 == xor8 within 16-lane row
  v += __shfl_xor(v, 16, 64);
  v += __shfl_xor(v, 32, 64);
  return v;
}

// ---------------- CSR build ----------------
__global__ __launch_bounds__(256) void k_hist(const int* __restrict__ eidx, const float* __restrict__ pw,
                                              u64* __restrict__ pk){
  int e = blockIdx.x*256 + threadIdx.x;
  if(e < N_EDGES){
    int d = eidx[N_EDGES + e];
    u64 q = (u64)(pw[e] * 67108864.f);
    atomicAdd(&pk[d], (1ull<<40) | q);
  }
}

__global__ __launch_bounds__(256) void k_scan1(const u64* __restrict__ pk, int* __restrict__ rowptr,
                                               int* __restrict__ bsum){
  __shared__ int sc[256];
  int b = blockIdx.x, t = threadIdx.x;
  int i = b*256 + t;
  int v = (i < N_NODES) ? (int)(pk[i] >> 40) : 0;
  sc[t] = v;
  __syncthreads();
  for(int off=1; off<256; off<<=1){
    int x = (t>=off)? sc[t-off] : 0;
    __syncthreads();
    sc[t] += x;
    __syncthreads();
  }
  if(i < N_NODES) rowptr[i] = sc[t] - v;
  if(t == 255) bsum[b] = sc[255];
}

__global__ __launch_bounds__(256) void k_scan2(const int* __restrict__ bsum, int* __restrict__ bbase,
                                               int* __restrict__ rowptr, int* __restrict__ gstart,
                                               int* __restrict__ gend){
  __shared__ int sc[256];
  int t = threadIdx.x;
  int v = (t < 196) ? bsum[t] : 0;
  sc[t] = v;
  __syncthreads();
  for(int off=1; off<256; off<<=1){
    int x = (t>=off)? sc[t-off] : 0;
    __syncthreads();
    sc[t] += x;
    __syncthreads();
  }
  if(t < 196) bbase[t] = sc[t] - v;
  if(t == 255) rowptr[N_NODES] = sc[255];
  if(t < 64){ gstart[t] = N_NODES; gend[t] = 0; }
}

__global__ __launch_bounds__(256) void k_scan3(int* __restrict__ rowptr, const int* __restrict__ bbase){
  int b = blockIdx.x, t = threadIdx.x;
  int i = b*256 + t;
  if(i < N_NODES) rowptr[i] += bbase[b];
}

// Block-aggregated binning: per-edge work stays in LDS; global atomics only
// per (block,bucket) (196*391 ~ 77k, ~10x fewer than per-edge). Output ebuf
// written coalesced in bucket-sorted runs. Record: x = s | (d&127)<<17, y = ge.
__global__ __launch_bounds__(256) void k_bin(const int* __restrict__ eidx, const float* __restrict__ pw,
                                             const u64* __restrict__ pk, const int* __restrict__ rowptr,
                                             int* __restrict__ fill, int* __restrict__ bcnt,
                                             uint2* __restrict__ ebuf, uint2* __restrict__ s_srcw){
  __shared__ int hist[NBUCK];
  __shared__ int scn[NBUCK];
  __shared__ int gbs[NBUCK];
  __shared__ uint2 lbuf[EPB];
  __shared__ unsigned short sbkt[EPB];
  int t = threadIdx.x;
  int e0 = blockIdx.x*EPB;
  int ne = N_EDGES - e0; if(ne > EPB) ne = EPB;
  for(int i=t;i<NBUCK;i+=256) hist[i] = 0;
  __syncthreads();
  for(int i=t;i<ne;i+=256) atomicAdd(&hist[eidx[N_EDGES + e0 + i] >> BSHIFT], 1);
  __syncthreads();
  for(int i=t;i<NBUCK;i+=256) scn[i] = hist[i];
  __syncthreads();
  // inclusive Hillis-Steele scan over scn[0..NBUCK)
  for(int off=1; off<NBUCK; off<<=1){
    int i0 = t, i1 = t + 256;
    int v0 = (i0 < NBUCK && i0 >= off) ? scn[i0-off] : 0;
    int v1 = (i1 < NBUCK && i1 >= off) ? scn[i1-off] : 0;
    __syncthreads();
    if(i0 < NBUCK) scn[i0] += v0;
    if(i1 < NBUCK) scn[i1] += v1;
    __syncthreads();
  }
  for(int i=t;i<NBUCK;i+=256){
    int c = hist[i];
    gbs[i] = c ? atomicAdd(&bcnt[i], c) : 0;   // one global atomic per (block,bucket)
    scn[i] -= c;                               // exclusive base
    hist[i] = 0;                               // reuse as rank counter
  }
  __syncthreads();
  for(int i=t;i<ne;i+=256){
    int e = e0 + i;
    int d = eidx[N_EDGES + e];
    int s = eidx[e];
    float ge = rsqrtf(degof(pk[s]) + 1.f) * pw[e];
    int b = d >> BSHIFT;
    int slot = scn[b] + atomicAdd(&hist[b], 1);
    uint2 r; r.x = (u32)s | ((u32)(d & ((1<<BSHIFT)-1)) << 17); r.y = __float_as_uint(ge);
    lbuf[slot] = r;
    sbkt[slot] = (unsigned short)b;
  }
  __syncthreads();
  for(int i=t;i<ne;i+=256){
    uint2 r = lbuf[i];
    int b = (int)sbkt[i];
    int rel = gbs[b] + (i - scn[b]);
    if(rel < BCAP){
      ebuf[(size_t)b*BCAP + rel] = r;          // coalesced runs per bucket segment
    } else {
      // overflow fallback: place from the END of the row (never collides with
      // k_place's front-fill since front+back counts sum to the row length)
      int d = (b << BSHIFT) + (int)(r.x >> 17);
      int pos = rowptr[d+1] - 1 - atomicAdd(&fill[d], 1);
      uint2 pr; pr.x = r.x & 0x1FFFFu; pr.y = r.y;
      s_srcw[pos] = pr;
    }
  }
}

// One block per bucket; fill counters live in LDS; final CSR writes land in a
// ~16KB window -> lines fill while L2-hot, writeback ~= payload.
__global__ __launch_bounds__(256) void k_place(const int* __restrict__ bcnt, const uint2* __restrict__ ebuf,
                                               const int* __restrict__ rowptr, uint2* __restrict__ s_srcw){
  __shared__ int lrow[128];
  __shared__ int lfill[128];
  int b = blockIdx.x, t = threadIdx.x;
  if(t < 128){
    int n = (b << BSHIFT) + t;
    lrow[t] = (n < N_NODES) ? rowptr[n] : 0;
    lfill[t] = 0;
  }
  __syncthreads();
  int cnt = bcnt[b]; if(cnt > BCAP) cnt = BCAP;
  const uint2* eb = ebuf + (size_t)b*BCAP;
  for(int i=t;i<cnt;i+=256){
    uint2 r = eb[i];
    int dloc = (int)(r.x >> 17);
    int pos = lrow[dloc] + atomicAdd(&lfill[dloc], 1);
    uint2 pr; pr.x = r.x & 0x1FFFFu; pr.y = r.y;
    s_srcw[pos] = pr;
  }
}

// ---------------- GCN ----------------
__global__ __launch_bounds__(256) void k_h(const float* __restrict__ px, const float* __restrict__ gw,
                                           u32* __restrict__ hb){
  int n = blockIdx.x*256 + threadIdx.x;
  if(n >= N_NODES) return;
  float x[33];
  #pragma unroll
  for(int k=0;k<33;k++) x[k] = px[n*33+k];
  float a[33];
  for(int c=0;c<33;c++){
    float s = 0.f;
    #pragma unroll
    for(int k=0;k<33;k++) s = fmaf(x[k], gw[c*33+k], s);
    a[c] = s;
  }
  #pragma unroll
  for(int d=0;d<16;d++) hb[(size_t)n*17 + d] = packbf(a[2*d], a[2*d+1]);
  hb[(size_t)n*17 + 16] = packbf(a[32], 0.f);
}

__global__ __launch_bounds__(256) void k_gcn(const u32* __restrict__ hb, const int* __restrict__ rowptr,
                                             const uint2* __restrict__ s_srcw,
                                             const u64* __restrict__ pk,
                                             const float* __restrict__ gcnb, const float* __restrict__ bnm,
                                             const float* __restrict__ bnv, const float* __restrict__ bnw,
                                             const float* __restrict__ bnb, float* __restrict__ xp1){
  int wave = threadIdx.x >> 6;
  int lane = threadIdx.x & 63;
  int n = blockIdx.x*4 + wave;
  if(n >= N_NODES) return;
  int l = lane & 15, g = lane >> 4;
  bool t0 = (l == 0);
  float dn = rsqrtf(degof(pk[n]) + 1.f);
  const u32* srow = hb + (size_t)n*17;
  u32 us  = srow[l];
  u32 ust = t0 ? srow[16] : 0u;
  float acc0, acc1, acct;
  if(g == 0){ acc0 = dn*bflo(us); acc1 = dn*bfhi(us); acct = dn*bflo(ust); }
  else      { acc0 = 0.f; acc1 = 0.f; acct = 0.f; }
  int rb = rowptr[n], re = rowptr[n+1];
  int j = rb;
  for(; j+8 <= re; j += 8){
    uint2 prA = s_srcw[j + g];
    uint2 prB = s_srcw[j + 4 + g];
    float geA = __uint_as_float(prA.y);
    float geB = __uint_as_float(prB.y);
    const u32* rA = hb + (size_t)prA.x*17;
    const u32* rB = hb + (size_t)prB.x*17;
    u32 uA  = rA[l], uB = rB[l];
    u32 utA = t0 ? rA[16] : 0u;
    u32 utB = t0 ? rB[16] : 0u;
    acc0 = fmaf(geA, bflo(uA),  fmaf(geB, bflo(uB),  acc0));
    acc1 = fmaf(geA, bfhi(uA),  fmaf(geB, bfhi(uB),  acc1));
    acct = fmaf(geA, bflo(utA), fmaf(geB, bflo(utB), acct));
  }
  if(j+4 <= re){
    uint2 pr = s_srcw[j + g];
    float ge = __uint_as_float(pr.y);
    const u32* r = hb + (size_t)pr.x*17;
    u32 u  = r[l];
    u32 ut = t0 ? r[16] : 0u;
    acc0 = fmaf(ge, bflo(u),  acc0);
    acc1 = fmaf(ge, bfhi(u),  acc1);
    acct = fmaf(ge, bflo(ut), acct);
    j += 4;
  }
  int rem = re - j;
  if(rem > 0){
    bool val = (g < rem);
    uint2 pr = s_srcw[val ? (j + g) : j];
    float ge = val ? __uint_as_float(pr.y) : 0.f;
    const u32* r = hb + (size_t)pr.x*17;
    u32 u  = r[l];
    u32 ut = t0 ? r[16] : 0u;
    acc0 = fmaf(ge, bflo(u),  acc0);
    acc1 = fmaf(ge, bfhi(u),  acc1);
    acct = fmaf(ge, bflo(ut), acct);
  }
  #pragma unroll
  for(int m=16;m<=32;m<<=1){
    acc0 += __shfl_xor(acc0, m, 64);
    acc1 += __shfl_xor(acc1, m, 64);
    acct += __shfl_xor(acct, m, 64);
  }
  if(g == 0){
    int c0 = 2*l, c1 = 2*l+1;
    float v0 = fmaxf(dn*acc0 + gcnb[c0], 0.f);
    float v1 = fmaxf(dn*acc1 + gcnb[c1], 0.f);
    float i0 = bnw[c0] / sqrtf(bnv[c0] + BN_EPS);
    float i1 = bnw[c1] / sqrtf(bnv[c1] + BN_EPS);
    float2 o;
    o.x = v0*i0 + (bnb[c0] - bnm[c0]*i0);
    o.y = v1*i1 + (bnb[c1] - bnm[c1]*i1);
    ((float2*)(xp1 + (size_t)n*36))[l] = o;
    if(t0){
      float vt = fmaxf(dn*acct + gcnb[32], 0.f);
      float it = bnw[32] / sqrtf(bnv[32] + BN_EPS);
      float2 ot; ot.x = vt*it + (bnb[32] - bnm[32]*it); ot.y = 0.f;
      ((float2*)(xp1 + (size_t)n*36))[16] = ot;
      float2 z; z.x = 0.f; z.y = 0.f;
      ((float2*)(xp1 + (size_t)n*36))[17] = z;
    }
  }
}

// ---------------- GATv2 ----------------
// xlb row layout (stride 72 u32): per head h at h*36: slots 0..31 = ch 0..63
// (fp16 pairs), slot 32 = ch 64,65 (fp16), slot 33 = fp32 bits of slope/ln2*dotL,
// slots 34,35 pad (16B alignment for uint4 reads of both heads).
// dotL[n,h] = sum_c att[h,c]*xl[n,h,c] = (sum_c att[h,c]*WL[h,c,:]) . x[n]
//           = u[h] . x[n]  -- u precontracted per block (no atomics).
__global__ __launch_bounds__(320) void k_gatlin(const float* __restrict__ xp1, const float* __restrict__ wl,
                                                const float* __restrict__ wr, const float* __restrict__ att,
                                                u32* __restrict__ xlb, float* __restrict__ xr){
  __shared__ float sx[64*36];
  __shared__ float swle[66*33];
  __shared__ float swlo[66*33];
  __shared__ float swre[66*33];
  __shared__ float swro[66*33];
  __shared__ float su[2][33];
  int t = threadIdx.x;
  int n0 = blockIdx.x*64;
  int nn = N_NODES - n0; if(nn > 64) nn = 64;
  for(int i=t;i<2178;i+=320){
    int d = i/33, k = i - d*33;
    int gb = d*66 + k;
    swle[i] = wl[gb];
    swlo[i] = wl[gb+33];
    swre[i] = wr[gb];
    swro[i] = wr[gb+33];
  }
  int xcnt = nn*36;
  for(int i=t;i<xcnt;i+=320) sx[i] = xp1[(size_t)n0*36 + i];
  __syncthreads();
  // precontract u[h][k] = sum_dd att[h,2dd]*swle[(h*33+dd)*33+k] + att[h,2dd+1]*swlo[...]
  if(t < 66){
    int hh = (t >= 33) ? 1 : 0;
    int k = t - 33*hh;
    float s = 0.f;
    const float* ah = att + hh*66;
    #pragma unroll 3
    for(int dd=0;dd<33;dd++){
      int p = hh*33 + dd;
      s = fmaf(ah[2*dd],   swle[p*33+k], s);
      s = fmaf(ah[2*dd+1], swlo[p*33+k], s);
    }
    su[hh][k] = s;
  }
  if(t < 264){
    int ng = t/66, p = t - ng*66;
    int nbase = ng*16;
    float al0[16], al1[16], ar0[16], ar1[16];
    #pragma unroll
    for(int i=0;i<16;i++){ al0[i]=0.f; al1[i]=0.f; ar0[i]=0.f; ar1[i]=0.f; }
    const float* wle = swle + p*33;
    const float* wlo = swlo + p*33;
    const float* wre = swre + p*33;
    const float* wro = swro + p*33;
    for(int k=0;k<33;k++){
      float w0 = wle[k], w1 = wlo[k], w2 = wre[k], w3 = wro[k];
      const float* xcol = sx + nbase*36 + k;
      #pragma unroll
      for(int i=0;i<16;i++){
        float x = xcol[i*36];
        al0[i] = fmaf(x, w0, al0[i]);
        al1[i] = fmaf(x, w1, al1[i]);
        ar0[i] = fmaf(x, w2, ar0[i]);
        ar1[i] = fmaf(x, w3, ar1[i]);
      }
    }
    int head = (p >= 33) ? 1 : 0;
    int dd = p - 33*head;
    #pragma unroll
    for(int i=0;i<16;i++){
      int n = nbase + i;
      if(n < nn){
        size_t nidx = (size_t)(n0 + n);
        xlb[nidx*72 + head*36 + dd] = packh(al0[i], al1[i]);
        float2 v; v.x = ar0[i]; v.y = ar1[i];
        ((float2*)xr)[nidx*66 + p] = v;
      }
    }
  }
  __syncthreads();
  if(t < 128){
    int nl = t >> 1, hh = t & 1;
    if(nl < nn){
      const float* xv = sx + nl*36;
      float s = 0.f;
      #pragma unroll
      for(int k=0;k<33;k++) s = fmaf(su[hh][k], xv[k], s);
      xlb[(size_t)(n0 + nl)*72 + hh*36 + 33] =
        __float_as_uint(s * (LRELU_SLOPE*1.44269504089f));
    }
  }
}

// One block/node, 2 head-waves; wave = 8 x 8-lane groups; 8 edges in flight.
// Score decomposition: e/ln2 = sum_c att*(1-s)/ln2 * max(z,0) + s/ln2*(dotL[src]+dotR[dst]);
// dotR[dst] is per-destination-constant and cancels in the softmax, so dropped.
// Score path in fp16 packed math: v_pk_add_f16 + v_pk_max_f16 + v_dot2_f32_f16
// (3 inst / 2 channels vs 8 scalar). Accumulation stays f32 (unpack shared).
__global__ __launch_bounds__(128) void k_gat(const int* __restrict__ rowptr, const u32* __restrict__ srcx,
                                             const u32* __restrict__ xlb, const float* __restrict__ xr,
                                             const float* __restrict__ att, const float* __restrict__ gatb,
                                             float* __restrict__ xp2){
  const float ATT_SC = (1.f - LRELU_SLOPE) * 1.44269504089f;
  int n = blockIdx.x;
  int h = threadIdx.x >> 6;
  int lane = threadIdx.x & 63;
  int l8 = lane & 7, g8 = lane >> 3;
  bool t0 = (l8 == 0);
  bool g0 = (g8 == 0);
  // xr: channels 8*l8 .. 8*l8+7 of head h (per-node constants), packed to fp16
  const float* xrp = xr + (size_t)n*132 + h*66 + 8*l8;
  float2 x01 = ((const float2*)xrp)[0];
  float2 x23 = ((const float2*)xrp)[1];
  float2 x45 = ((const float2*)xrp)[2];
  float2 x67 = ((const float2*)xrp)[3];
  float2 xt  = t0 ? *(const float2*)(xr + (size_t)n*132 + h*66 + 64) : make_float2(0.f,0.f);
  u32 xh0 = packh(x01.x, x01.y);
  u32 xh1 = packh(x23.x, x23.y);
  u32 xh2 = packh(x45.x, x45.y);
  u32 xh3 = packh(x67.x, x67.y);
  u32 xht = t0 ? packh(xt.x, xt.y) : 0u;
  const float* ap = att + h*66 + 8*l8;
  float2 a01 = ((const float2*)ap)[0];
  float2 a23 = ((const float2*)ap)[1];
  float2 a45 = ((const float2*)ap)[2];
  float2 a67 = ((const float2*)ap)[3];
  float2 atl = *(const float2*)(att + h*66 + 64);
  u32 ah0 = packh(a01.x*ATT_SC, a01.y*ATT_SC);
  u32 ah1 = packh(a23.x*ATT_SC, a23.y*ATT_SC);
  u32 ah2 = packh(a45.x*ATT_SC, a45.y*ATT_SC);
  u32 ah3 = packh(a67.x*ATT_SC, a67.y*ATT_SC);
  u32 aht = packh(atl.x*ATT_SC, atl.y*ATT_SC);

  const u32* xbase = xlb + h*36;
  float v0,v1,v2,v3,v4,v5,v6,v7,w0,w1;

#define GSCORE(U, TU, P) { \
  u32 q0 = pkmax0(pkadd(U.x, xh0)); \
  u32 q1 = pkmax0(pkadd(U.y, xh1)); \
  u32 q2 = pkmax0(pkadd(U.z, xh2)); \
  u32 q3 = pkmax0(pkadd(U.w, xh3)); \
  u32 qt = pkmax0(pkadd(TU.x, xht)); \
  float pA = __uint_as_float(TU.y); \
  pA = dot2(q0, ah0, pA); \
  pA = dot2(q1, ah1, pA); \
  pA = dot2(q2, ah2, pA); \
  pA = dot2(q3, ah3, pA); \
  pA = dot2(qt, aht, pA); \
  v0 = hlo(U.x); v1 = hhi(U.x); \
  v2 = hlo(U.y); v3 = hhi(U.y); \
  v4 = hlo(U.z); v5 = hhi(U.z); \
  v6 = hlo(U.w); v7 = hhi(U.w); \
  w0 = hlo(TU.x); w1 = hhi(TU.x); \
  P = red8(pA); }

  // self score (all 8 groups compute identically -> all lanes get p_self)
  const u32* srow = xbase + (size_t)n*72;
  uint4 su = ((const uint4*)srow)[l8];
  uint2 stl = t0 ? ((const uint2*)srow)[16] : make_uint2(0u,0u);
  float ps;
  GSCORE(su, stl, ps);
  float cn = -ps;
  // seed accumulators with self contribution (weight exp2(0)=1) on group 0
  float A0 = g0? v0 : 0.f, A1 = g0? v1 : 0.f, A2 = g0? v2 : 0.f, A3 = g0? v3 : 0.f;
  float A4 = g0? v4 : 0.f, A5 = g0? v5 : 0.f, A6 = g0? v6 : 0.f, A7 = g0? v7 : 0.f;
  float T0 = g0? w0 : 0.f, T1 = g0? w1 : 0.f;
  float asum = g0 ? 1.f : 0.f;

  int rb = rowptr[n], re = rowptr[n+1];
  int j = rb;
  for(; j+8 <= re; j += 8){
    int s = (int)srcx[2*(j + g8)];
    const u32* r = xbase + (size_t)s*72;
    uint4 u = ((const uint4*)r)[l8];
    uint2 tu = t0 ? ((const uint2*)r)[16] : make_uint2(0u,0u);
    float p;
    GSCORE(u, tu, p);
    float a = __builtin_amdgcn_exp2f(p + cn);
    A0 = fmaf(a, v0, A0); A1 = fmaf(a, v1, A1); A2 = fmaf(a, v2, A2); A3 = fmaf(a, v3, A3);
    A4 = fmaf(a, v4, A4); A5 = fmaf(a, v5, A5); A6 = fmaf(a, v6, A6); A7 = fmaf(a, v7, A7);
    T0 = fmaf(a, w0, T0); T1 = fmaf(a, w1, T1);
    asum += a;
  }
  int rem = re - j;
  if(rem > 0){
    bool val = (g8 < rem);
    int s = val ? (int)srcx[2*(j + g8)] : n;
    const u32* r = xbase + (size_t)s*72;
    uint4 u = ((const uint4*)r)[l8];
    uint2 tu = t0 ? ((const uint2*)r)[16] : make_uint2(0u,0u);
    float p;
    GSCORE(u, tu, p);
    float a = val ? __builtin_amdgcn_exp2f(p + cn) : 0.f;
    A0 = fmaf(a, v0, A0); A1 = fmaf(a, v1, A1); A2 = fmaf(a, v2, A2); A3 = fmaf(a, v3, A3);
    A4 = fmaf(a, v4, A4); A5 = fmaf(a, v5, A5); A6 = fmaf(a, v6, A6); A7 = fmaf(a, v7, A7);
    T0 = fmaf(a, w0, T0); T1 = fmaf(a, w1, T1);
    asum += a;
  }
#undef GSCORE

  A0 = redall(A0); A1 = redall(A1); A2 = redall(A2); A3 = redall(A3);
  A4 = redall(A4); A5 = redall(A5); A6 = redall(A6); A7 = redall(A7);
  T0 = redall(T0); T1 = redall(T1);
  asum = redall(asum);

  if(g0){
    float inv = 1.f / asum;
    const float* gp = gatb + h*66 + 8*l8;
    float2 g01 = ((const float2*)gp)[0];
    float2 g23 = ((const float2*)gp)[1];
    float2 g45 = ((const float2*)gp)[2];
    float2 g67 = ((const float2*)gp)[3];
    float* op = xp2 + (size_t)n*132 + h*66 + 8*l8;
    float2 o;
    o.x = fmaxf(fmaf(A0,inv,g01.x),0.f); o.y = fmaxf(fmaf(A1,inv,g01.y),0.f); ((float2*)op)[0] = o;
    o.x = fmaxf(fmaf(A2,inv,g23.x),0.f); o.y = fmaxf(fmaf(A3,inv,g23.y),0.f); ((float2*)op)[1] = o;
    o.x = fmaxf(fmaf(A4,inv,g45.x),0.f); o.y = fmaxf(fmaf(A5,inv,g45.y),0.f); ((float2*)op)[2] = o;
    o.x = fmaxf(fmaf(A6,inv,g67.x),0.f); o.y = fmaxf(fmaf(A7,inv,g67.y),0.f); ((float2*)op)[3] = o;
    if(t0){
      float2 gt = *(const float2*)(gatb + h*66 + 64);
      float2 ot;
      ot.x = fmaxf(fmaf(T0,inv,gt.x),0.f); ot.y = fmaxf(fmaf(T1,inv,gt.y),0.f);
      *(float2*)(xp2 + (size_t)n*132 + h*66 + 64) = ot;
    }
  }
}

// ---------------- pooling + MLP head ----------------
__global__ __launch_bounds__(256) void k_bounds(const int* __restrict__ batch, int* __restrict__ gstart,
                                                int* __restrict__ gend){
  int n = blockIdx.x*256 + threadIdx.x;
  if(n >= N_NODES) return;
  int b = batch[n];
  if(n == 0) gstart[b] = 0;
  else {
    int p = batch[n-1];
    if(p != b){ gstart[b] = n; gend[p] = n; }
  }
  if(n == N_NODES-1) gend[b] = N_NODES;
}

__global__ __launch_bounds__(128) void k_poolp(const float* __restrict__ xp2, const int* __restrict__ gstart,
                                               const int* __restrict__ gend, float* __restrict__ pp){
  int g = blockIdx.x, seg = blockIdx.y, t = threadIdx.x;
  int s = gstart[g], e = gend[g];
  int len = e - s; if(len < 0) len = 0;
  int ns = s + (int)(((long long)len*seg)>>4);
  int ne = s + (int)(((long long)len*(seg+1))>>4);
  float a0 = 0.f, a1 = 0.f;
  for(int n=ns;n<ne;n++){
    a0 += xp2[(size_t)n*132 + t];
    if(t < 4) a1 += xp2[(size_t)n*132 + 128 + t];
  }
  float* o = pp + (size_t)(g*16 + seg)*132;
  o[t] = a0;
  if(t < 4) o[128 + t] = a1;
}

__global__ __launch_bounds__(256) void k_pfc1(const float* __restrict__ pp, const int* __restrict__ gstart,
                                              const int* __restrict__ gend, const float* __restrict__ w,
                                              const float* __restrict__ b, float* __restrict__ h1T){
  __shared__ float pooled[132];
  int g = blockIdx.x, t = threadIdx.x;
  if(t < 132){
    float s = 0.f;
    #pragma unroll
    for(int k=0;k<16;k++) s += pp[(size_t)(g*16 + k)*132 + t];
    int c = gend[g] - gstart[g]; if(c < 1) c = 1;
    pooled[t] = s/(float)c;
  }
  __syncthreads();
  #pragma unroll
  for(int r=0;r<4;r++){
    int o = r*256 + t;
    const float* wr = w + o*132;
    float acc = b[o];
    for(int k=0;k<132;k++) acc = fmaf(pooled[k], wr[k], acc);
    h1T[o*64+g] = fmaxf(acc, 0.f);
  }
}

__global__ __launch_bounds__(256) void k_fc2(const float* __restrict__ h1T, const float* __restrict__ w,
                                             const float* __restrict__ b, float* __restrict__ out){
  __shared__ float part[256];
  int o = blockIdx.x, t = threadIdx.x;
  int s = t >> 6, g = t & 63;
  const float* wr = w + o*1024 + s*256;
  const float* hp = h1T + (size_t)(s*256)*64 + g;
  float acc = 0.f;
  for(int k=0;k<256;k++) acc = fmaf(hp[k*64], wr[k], acc);
  part[t] = acc;
  __syncthreads();
  if(s == 0){
    float r = b[o] + part[g] + part[64+g] + part[128+g] + part[192+g];
    out[8192 + g*128 + o] = r;
  }
}

// ---------------- RNA branches ----------------
__global__ __launch_bounds__(256) void k_bucket(const int* __restrict__ g, int L, int V,
                                                int* __restrict__ sci, int* __restrict__ off){
  __shared__ int gl[3000];
  __shared__ int hist[65];
  __shared__ int base[66];
  int b = blockIdx.x, t = threadIdx.x;
  if(t < V) hist[t] = 0;
  for(int i=t;i<L;i+=256) gl[i] = g[b*L + i];
  __syncthreads();
  for(int i=t;i<L;i+=256) atomicAdd(&hist[gl[i]], 1);
  __syncthreads();
  if(t == 0){
    int run = 0;
    for(int v=0;v<V;v++){ base[v] = run; run += hist[v]; }
    base[V] = run;
  }
  __syncthreads();
  if(t <= V) off[b*(V+1) + t] = base[t];
  if(t < V) hist[t] = 0;
  __syncthreads();
  for(int i=t;i<L;i+=256){
    int v = gl[i];
    int p = base[v] + atomicAdd(&hist[v], 1);
    sci[b*3000 + p] = i*8;
  }
}

__global__ __launch_bounds__(256) void k_sgather(const int* __restrict__ sci, const int* __restrict__ off,
                                                 const float* __restrict__ w, int V, int wstride,
                                                 int sstride, float* __restrict__ S){
  __shared__ int loff[66];
  __shared__ int lci[3000];
  int b = blockIdx.x, q = blockIdx.y, t = threadIdx.x;
  int nsplit = gridDim.y;
  if(t <= V) loff[t] = off[b*(V+1) + t];
  __syncthreads();
  int vs = (V*q)/nsplit, ve = (V*(q+1))/nsplit;
  if(vs == ve) return;
  int p0 = loff[vs], p1 = loff[ve];
  for(int i=p0+t;i<p1;i+=256) lci[i-p0] = sci[b*3000 + i];
  __syncthreads();
  int co = t >> 3, kk = t & 7;
  const float* wrow = w + co*wstride + kk;
  float* Srow = S + (size_t)b*32*sstride + co*sstride + kk;
  for(int v=vs;v<ve;v++){
    int j = loff[v] - p0, je = loff[v+1] - p0;
    float a0=0.f,a1=0.f,a2=0.f,a3=0.f,a4=0.f,a5=0.f,a6=0.f,a7=0.f;
    for(; j+8 <= je; j += 8){
      a0 += wrow[lci[j]];
      a1 += wrow[lci[j+1]];
      a2 += wrow[lci[j+2]];
      a3 += wrow[lci[j+3]];
      a4 += wrow[lci[j+4]];
      a5 += wrow[lci[j+5]];
      a6 += wrow[lci[j+6]];
      a7 += wrow[lci[j+7]];
    }
    for(; j<je; j++) a0 += wrow[lci[j]];
    Srow[v*8] = ((a0+a1)+(a2+a3)) + ((a4+a5)+(a6+a7));
  }
}

__global__ __launch_bounds__(128) void k_y(const float* __restrict__ S1, const float* __restrict__ S2,
                                           const float* __restrict__ emb1, const float* __restrict__ emb2,
                                           const float* __restrict__ c1b, const float* __restrict__ c2b,
                                           float* __restrict__ ysum){
  __shared__ float em1[640];
  __shared__ float em2[8320];
  __shared__ float Sa[320];
  __shared__ float Sb[4160];
  int b = blockIdx.x, cg = blockIdx.y, t = threadIdx.x;
  for(int i=t;i<640;i+=128)  em1[i] = emb1[i];
  for(int i=t;i<8320;i+=128) em2[i] = emb2[i];
  for(int i=t;i<320;i+=128)  Sa[i] = S1[b*1280 + cg*320 + i];
  for(int i=t;i<4160;i+=128) Sb[i] = S2[(size_t)b*16640 + cg*4160 + i];
  __syncthreads();
  if(t >= 121) return;
  #pragma unroll
  for(int c8=0;c8<8;c8++){
    int co = cg*8 + c8;
    const float* sa = Sa + c8*40;
    float acc1 = c1b[co];
    #pragma unroll
    for(int v=0;v<5;v++)
      #pragma unroll
      for(int k=0;k<8;k++) acc1 = fmaf(sa[v*8+k], em1[v*128 + t + k], acc1);
    const float* sb = Sb + c8*520;
    float acc2 = c2b[co];
    for(int v=0;v<65;v++){
      #pragma unroll
      for(int k=0;k<8;k++) acc2 = fmaf(sb[v*8+k], em2[v*128 + t + k], acc2);
    }
    ysum[b*3872 + co*121 + t] = 0.5f*(acc1 + acc2);
  }
}

__global__ __launch_bounds__(256) void k_fcxr(const float* __restrict__ ysum, const float* __restrict__ fcw,
                                              const float* __restrict__ fcb, float* __restrict__ out){
  __shared__ float part[512];
  int bp = blockIdx.x, q = blockIdx.y, t = threadIdx.x;
  int b0 = bp*2;
  int ol = t >> 3;
  int o  = q*32 + ol;
  int slice = t & 7;
  const float4* ys0 = (const float4*)(ysum + b0*3872) + slice*121;
  const float4* ys1 = (const float4*)(ysum + (b0+1)*3872) + slice*121;
  const float4* wr  = (const float4*)(fcw + (size_t)o*3872) + slice*121;
  float acc0 = 0.f, acc1 = 0.f;
  for(int k=0;k<121;k++){
    float4 w4 = wr[k];
    float4 y0 = ys0[k], y1 = ys1[k];
    acc0 += y0.x*w4.x + y0.y*w4.y + y0.z*w4.z + y0.w*w4.w;
    acc1 += y1.x*w4.x + y1.y*w4.y + y1.z*w4.z + y1.w*w4.w;
  }
  part[t] = acc0;
  part[256+t] = acc1;
  __syncthreads();
  if(slice == 0){
    float s0 = fcb[o], s1 = fcb[o];
    #pragma unroll
    for(int i=0;i<8;i++){ s0 += part[ol*8 + i]; s1 += part[256 + ol*8 + i]; }
    out[b0*128 + o] = s0;
    out[(b0+1)*128 + o] = s1;
  }
}

extern "C" void kernel_launch(void* const* d_in, const int* in_sizes, int n_in,
                              void* d_out, int out_size, void* d_ws, size_t ws_size,
                              hipStream_t stream){
  const int*   g_rna = (const int*)  d_in[0];
  const int*   l_rna = (const int*)  d_in[1];
  const float* pro_x = (const float*)d_in[2];
  const int*   eidx  = (const int*)  d_in[3];
  const float* pro_w = (const float*)d_in[4];
  const int*   batch = (const int*)  d_in[5];
  const float* emb1  = (const float*)d_in[6];
  const float* emb2  = (const float*)d_in[7];
  const float* c1w   = (const float*)d_in[8];
  const float* c1b   = (const float*)d_in[9];
  const float* c2w   = (const float*)d_in[10];
  const float* c2b   = (const float*)d_in[11];
  const float* fcxw  = (const float*)d_in[12];
  const float* fcxb  = (const float*)d_in[13];
  const float* gcnw  = (const float*)d_in[14];
  const float* gcnb  = (const float*)d_in[15];
  const float* bnm   = (const float*)d_in[16];
  const float* bnv   = (const float*)d_in[17];
  const float* bnw   = (const float*)d_in[18];
  const float* bnb   = (const float*)d_in[19];
  const float* gwl   = (const float*)d_in[20];
  const float* gwr   = (const float*)d_in[21];
  const float* gatt  = (const float*)d_in[22];
  const float* gatb  = (const float*)d_in[23];
  const float* f1w   = (const float*)d_in[24];
  const float* f1b   = (const float*)d_in[25];
  const float* f2w   = (const float*)d_in[26];
  const float* f2b_  = (const float*)d_in[27];
  float* out = (float*)d_out;

  char* ws = (char*)d_ws;
  size_t off = 0;
  auto A = [&](size_t n)->char*{ char* p = ws + off; off = (off + n + 255) & ~(size_t)255; return p; };
  u64*   pk     = (u64*)  A((size_t)N_NODES*8);
  int*   fill   = (int*)  A((size_t)N_NODES*4);
  int*   bcnt   = (int*)  A((size_t)NBUCK*4);
  size_t zero_bytes = off;
  int*   rowptr = (int*)  A((size_t)(N_NODES+1)*4);
  int*   bsum   = (int*)  A(196*4);
  int*   bbase  = (int*)  A(196*4);
  uint2* s_srcw = (uint2*)A((size_t)N_EDGES*8);
  u32*   hb     = (u32*)  A((size_t)N_NODES*17*4);
  float* xp1    = (float*)A((size_t)N_NODES*36*4);
  u32*   xlb    = (u32*)  A((size_t)N_NODES*72*4);
  float* xr     = (float*)A((size_t)N_NODES*132*4);
  float* xp2    = (float*)A((size_t)N_NODES*132*4);
  int*   gstart = (int*)  A(64*4);
  int*   gend   = (int*)  A(64*4);
  float* pp     = (float*)A((size_t)64*16*132*4);
  float* h1T    = (float*)A(1024*64*4);
  float* S1     = (float*)A((size_t)64*1280*4);
  float* S2     = (float*)A((size_t)64*16640*4);
  float* ysum   = (float*)A((size_t)64*3872*4);
  int*   sci1   = (int*)  A((size_t)64*3000*4);
  int*   off1   = (int*)  A((size_t)64*8*4);
  int*   sci2   = (int*)  A((size_t)64*3000*4);
  int*   off2   = (int*)  A((size_t)64*66*4);
  (void)ws_size; (void)in_sizes; (void)n_in; (void)out_size;

  // ebuf (12.8 MB, uint2 records) aliases xr (26.4 MB): dead until k_gatlin,
  // and the CSR build completes (stream-ordered) before k_gatlin writes xr.
  uint2* ebuf = (uint2*)xr;

  hipMemsetAsync(ws, 0, zero_bytes, stream);

  // protein GNN pipeline
  k_hist   <<<3125, 256, 0, stream>>>(eidx, pro_w, pk);
  k_scan1  <<<196, 256, 0, stream>>>(pk, rowptr, bsum);
  k_scan2  <<<1, 256, 0, stream>>>(bsum, bbase, rowptr, gstart, gend);
  k_scan3  <<<196, 256, 0, stream>>>(rowptr, bbase);
  k_bin    <<<NBLKBIN, 256, 0, stream>>>(eidx, pro_w, pk, rowptr, fill, bcnt, ebuf, s_srcw);
  k_place  <<<NBUCK, 256, 0, stream>>>(bcnt, ebuf, rowptr, s_srcw);
  k_h      <<<196, 256, 0, stream>>>(pro_x, gcnw, hb);
  k_gcn    <<<12500, 256, 0, stream>>>(hb, rowptr, s_srcw, pk, gcnb, bnm, bnv, bnw, bnb, xp1);
  k_gatlin <<<782, 320, 0, stream>>>(xp1, gwl, gwr, gatt, xlb, xr);
  k_gat    <<<N_NODES, 128, 0, stream>>>(rowptr, (const u32*)s_srcw, xlb, xr, gatt, gatb, xp2);
  k_bounds <<<196, 256, 0, stream>>>(batch, gstart, gend);
  k_poolp  <<<dim3(64,16), 128, 0, stream>>>(xp2, gstart, gend, pp);
  k_pfc1   <<<64, 256, 0, stream>>>(pp, gstart, gend, f1w, f1b, h1T);
  k_fc2    <<<128, 256, 0, stream>>>(h1T, f2w, f2b_, out);

  // RNA branches
  k_bucket <<<64, 256, 0, stream>>>(g_rna, 3000, 5, sci1, off1);
  k_bucket <<<64, 256, 0, stream>>>(l_rna, 2998, 65, sci2, off2);
  k_sgather<<<dim3(64,5), 256, 0, stream>>>(sci1, off1, c1w, 5, 24000, 40, S1);
  k_sgather<<<dim3(64,32), 256, 0, stream>>>(sci2, off2, c2w, 65, 23984, 520, S2);
  k_y      <<<dim3(64,4), 128, 0, stream>>>(S1, S2, emb1, emb2, c1b, c2b, ysum);
  k_fcxr   <<<dim3(32,4), 256, 0, stream>>>(ysum, fcxw, fcxb, out);
}

// Round 7
// 546.687 us; speedup vs baseline: 1.0020x; 1.0020x over previous
//
#include <hip/hip_runtime.h>

#define N_NODES 50000
#define N_EDGES 800000
#define LRELU_SLOPE 0.2f
#define BN_EPS 1e-5f

#define BSHIFT 7
#define NBUCK 391            // ceil(50000/128)
#define BCAP 4096            // mean 2048/bucket; overflow falls back (correct for any dist)
#define EPB 4096             // edges per k_bin block
#define NBLKBIN ((N_EDGES + EPB - 1)/EPB)

typedef unsigned int u32;
typedef unsigned long long u64;

__device__ __forceinline__ float lrelu(float x){ return fmaxf(x,0.f) + LRELU_SLOPE*fminf(x,0.f); }
__device__ __forceinline__ float bflo(u32 u){ return __uint_as_float(u<<16); }
__device__ __forceinline__ float bfhi(u32 u){ return __uint_as_float(u & 0xffff0000u); }
__device__ __forceinline__ u32 packbf(float a, float b){
  u32 ua = __float_as_uint(a); ua = (ua + 0x7fffu + ((ua>>16)&1u)) >> 16;
  u32 ub = __float_as_uint(b); ub = (ub + 0x7fffu + ((ub>>16)&1u)) >> 16;
  return ua | (ub<<16);
}

// fp16 pair in a u32 -- no hip_fp16.h API (header lacks __hmax2 on this ROCm).
typedef _Float16 h2v __attribute__((ext_vector_type(2)));
union uhcv { u32 i; h2v h; };
__device__ __forceinline__ u32 packh(float a, float b){
  uhcv c; c.h.x = (_Float16)a; c.h.y = (_Float16)b; return c.i;
}
__device__ __forceinline__ float hlo(u32 u){ uhcv c; c.i = u; return (float)c.h.x; }
__device__ __forceinline__ float hhi(u32 u){ uhcv c; c.i = u; return (float)c.h.y; }
__device__ __forceinline__ h2v toh2(u32 u){ uhcv c; c.i = u; return c.h; }
// packed fp16 ops via asm (VOP3P, baseline gfx9+)
__device__ __forceinline__ u32 pkadd(u32 a, u32 b){
  u32 r; asm("v_pk_add_f16 %0, %1, %2" : "=v"(r) : "v"(a), "v"(b)); return r;
}
__device__ __forceinline__ u32 pkmax0(u32 a){
  u32 r; asm("v_pk_max_f16 %0, %1, %2" : "=v"(r) : "v"(a), "v"(0u)); return r;
}
__device__ __forceinline__ float dot2(u32 a, u32 b, float c){
#if defined(__has_builtin) && __has_builtin(__builtin_amdgcn_fdot2)
  return __builtin_amdgcn_fdot2(toh2(a), toh2(b), c, false);
#else
  float r; asm("v_dot2_f32_f16 %0, %1, %2, %3" : "=v"(r) : "v"(a), "v"(b), "v"(c)); return r;
#endif
}

// packed (cnt<<40 | deg in 2^-26 fixed point)
__device__ __forceinline__ float degof(u64 p){
  return (float)(p & 0xFFFFFFFFFFull) * (1.0f/67108864.0f);
}

// DPP-fused adds: VALU-only lane reduction (no ds_swizzle).
template<int CTRL>
__device__ __forceinline__ float dppadd(float x){
  int y = __builtin_amdgcn_update_dpp(0, __float_as_int(x), CTRL, 0xF, 0xF, false);
  return x + __int_as_float(y);
}
// sum over 8-lane group (lanes differing in bits 0..2)
__device__ __forceinline__ float red8(float p){
  p = dppadd<0x141>(p);  // row_half_mirror: reverse within 8
  p = dppadd<0x4E>(p);   // quad_perm [2,3,0,1] = xor2
  p = dppadd<0xB1>(p);   // quad_perm [1,0,3,2] = xor1
  return p;
}
// sum across the 8 groups (lane bits 3,4,5), keeping l8 lanes separate
__device__ __forceinline__ float redall(float v){
  v = dppadd<0x128>(v);          // row_ror:8 == xor8 within 16-lane row
  v += __shfl_xor(v, 16, 64);
  v += __shfl_xor(v, 32, 64);
  return v;
}

// ---------------- CSR build ----------------
__global__ __launch_bounds__(256) void k_hist(const int* __restrict__ eidx, const float* __restrict__ pw,
                                              u64* __restrict__ pk){
  int e = blockIdx.x*256 + threadIdx.x;
  if(e < N_EDGES){
    int d = eidx[N_EDGES + e];
    u64 q = (u64)(pw[e] * 67108864.f);
    atomicAdd(&pk[d], (1ull<<40) | q);
  }
}

__global__ __launch_bounds__(256) void k_scan1(const u64* __restrict__ pk, int* __restrict__ rowptr,
                                               int* __restrict__ bsum){
  __shared__ int sc[256];
  int b = blockIdx.x, t = threadIdx.x;
  int i = b*256 + t;
  int v = (i < N_NODES) ? (int)(pk[i] >> 40) : 0;
  sc[t] = v;
  __syncthreads();
  for(int off=1; off<256; off<<=1){
    int x = (t>=off)? sc[t-off] : 0;
    __syncthreads();
    sc[t] += x;
    __syncthreads();
  }
  if(i < N_NODES) rowptr[i] = sc[t] - v;
  if(t == 255) bsum[b] = sc[255];
}

__global__ __launch_bounds__(256) void k_scan2(const int* __restrict__ bsum, int* __restrict__ bbase,
                                               int* __restrict__ rowptr, int* __restrict__ gstart,
                                               int* __restrict__ gend){
  __shared__ int sc[256];
  int t = threadIdx.x;
  int v = (t < 196) ? bsum[t] : 0;
  sc[t] = v;
  __syncthreads();
  for(int off=1; off<256; off<<=1){
    int x = (t>=off)? sc[t-off] : 0;
    __syncthreads();
    sc[t] += x;
    __syncthreads();
  }
  if(t < 196) bbase[t] = sc[t] - v;
  if(t == 255) rowptr[N_NODES] = sc[255];
  if(t < 64){ gstart[t] = N_NODES; gend[t] = 0; }
}

__global__ __launch_bounds__(256) void k_scan3(int* __restrict__ rowptr, const int* __restrict__ bbase){
  int b = blockIdx.x, t = threadIdx.x;
  int i = b*256 + t;
  if(i < N_NODES) rowptr[i] += bbase[b];
}

// Block-aggregated binning: per-edge work stays in LDS; global atomics only
// per (block,bucket) (196*391 ~ 77k, ~10x fewer than per-edge). Output ebuf
// written coalesced in bucket-sorted runs. Record: x = s | (d&127)<<17, y = ge.
__global__ __launch_bounds__(256) void k_bin(const int* __restrict__ eidx, const float* __restrict__ pw,
                                             const u64* __restrict__ pk, const int* __restrict__ rowptr,
                                             int* __restrict__ fill, int* __restrict__ bcnt,
                                             uint2* __restrict__ ebuf, uint2* __restrict__ s_srcw){
  __shared__ int hist[NBUCK];
  __shared__ int scn[NBUCK];
  __shared__ int gbs[NBUCK];
  __shared__ uint2 lbuf[EPB];
  __shared__ unsigned short sbkt[EPB];
  int t = threadIdx.x;
  int e0 = blockIdx.x*EPB;
  int ne = N_EDGES - e0; if(ne > EPB) ne = EPB;
  for(int i=t;i<NBUCK;i+=256) hist[i] = 0;
  __syncthreads();
  for(int i=t;i<ne;i+=256) atomicAdd(&hist[eidx[N_EDGES + e0 + i] >> BSHIFT], 1);
  __syncthreads();
  for(int i=t;i<NBUCK;i+=256) scn[i] = hist[i];
  __syncthreads();
  // inclusive Hillis-Steele scan over scn[0..NBUCK)
  for(int off=1; off<NBUCK; off<<=1){
    int i0 = t, i1 = t + 256;
    int v0 = (i0 < NBUCK && i0 >= off) ? scn[i0-off] : 0;
    int v1 = (i1 < NBUCK && i1 >= off) ? scn[i1-off] : 0;
    __syncthreads();
    if(i0 < NBUCK) scn[i0] += v0;
    if(i1 < NBUCK) scn[i1] += v1;
    __syncthreads();
  }
  for(int i=t;i<NBUCK;i+=256){
    int c = hist[i];
    gbs[i] = c ? atomicAdd(&bcnt[i], c) : 0;   // one global atomic per (block,bucket)
    scn[i] -= c;                               // exclusive base
    hist[i] = 0;                               // reuse as rank counter
  }
  __syncthreads();
  for(int i=t;i<ne;i+=256){
    int e = e0 + i;
    int d = eidx[N_EDGES + e];
    int s = eidx[e];
    float ge = rsqrtf(degof(pk[s]) + 1.f) * pw[e];
    int b = d >> BSHIFT;
    int slot = scn[b] + atomicAdd(&hist[b], 1);
    uint2 r; r.x = (u32)s | ((u32)(d & ((1<<BSHIFT)-1)) << 17); r.y = __float_as_uint(ge);
    lbuf[slot] = r;
    sbkt[slot] = (unsigned short)b;
  }
  __syncthreads();
  for(int i=t;i<ne;i+=256){
    uint2 r = lbuf[i];
    int b = (int)sbkt[i];
    int rel = gbs[b] + (i - scn[b]);
    if(rel < BCAP){
      ebuf[(size_t)b*BCAP + rel] = r;          // coalesced runs per bucket segment
    } else {
      // overflow fallback: place from the END of the row (never collides with
      // k_place's front-fill since front+back counts sum to the row length)
      int d = (b << BSHIFT) + (int)(r.x >> 17);
      int pos = rowptr[d+1] - 1 - atomicAdd(&fill[d], 1);
      uint2 pr; pr.x = r.x & 0x1FFFFu; pr.y = r.y;
      s_srcw[pos] = pr;
    }
  }
}

// One block per bucket; fill counters live in LDS; final CSR writes land in a
// ~16KB window -> lines fill while L2-hot, writeback ~= payload.
__global__ __launch_bounds__(256) void k_place(const int* __restrict__ bcnt, const uint2* __restrict__ ebuf,
                                               const int* __restrict__ rowptr, uint2* __restrict__ s_srcw){
  __shared__ int lrow[128];
  __shared__ int lfill[128];
  int b = blockIdx.x, t = threadIdx.x;
  if(t < 128){
    int n = (b << BSHIFT) + t;
    lrow[t] = (n < N_NODES) ? rowptr[n] : 0;
    lfill[t] = 0;
  }
  __syncthreads();
  int cnt = bcnt[b]; if(cnt > BCAP) cnt = BCAP;
  const uint2* eb = ebuf + (size_t)b*BCAP;
  for(int i=t;i<cnt;i+=256){
    uint2 r = eb[i];
    int dloc = (int)(r.x >> 17);
    int pos = lrow[dloc] + atomicAdd(&lfill[dloc], 1);
    uint2 pr; pr.x = r.x & 0x1FFFFu; pr.y = r.y;
    s_srcw[pos] = pr;
  }
}

// ---------------- GCN ----------------
__global__ __launch_bounds__(256) void k_h(const float* __restrict__ px, const float* __restrict__ gw,
                                           u32* __restrict__ hb){
  int n = blockIdx.x*256 + threadIdx.x;
  if(n >= N_NODES) return;
  float x[33];
  #pragma unroll
  for(int k=0;k<33;k++) x[k] = px[n*33+k];
  float a[33];
  for(int c=0;c<33;c++){
    float s = 0.f;
    #pragma unroll
    for(int k=0;k<33;k++) s = fmaf(x[k], gw[c*33+k], s);
    a[c] = s;
  }
  #pragma unroll
  for(int d=0;d<16;d++) hb[(size_t)n*17 + d] = packbf(a[2*d], a[2*d+1]);
  hb[(size_t)n*17 + 16] = packbf(a[32], 0.f);
}

__global__ __launch_bounds__(256) void k_gcn(const u32* __restrict__ hb, const int* __restrict__ rowptr,
                                             const uint2* __restrict__ s_srcw,
                                             const u64* __restrict__ pk,
                                             const float* __restrict__ gcnb, const float* __restrict__ bnm,
                                             const float* __restrict__ bnv, const float* __restrict__ bnw,
                                             const float* __restrict__ bnb, float* __restrict__ xp1){
  int wave = threadIdx.x >> 6;
  int lane = threadIdx.x & 63;
  int n = blockIdx.x*4 + wave;
  if(n >= N_NODES) return;
  int l = lane & 15, g = lane >> 4;
  bool t0 = (l == 0);
  float dn = rsqrtf(degof(pk[n]) + 1.f);
  const u32* srow = hb + (size_t)n*17;
  u32 us  = srow[l];
  u32 ust = t0 ? srow[16] : 0u;
  float acc0, acc1, acct;
  if(g == 0){ acc0 = dn*bflo(us); acc1 = dn*bfhi(us); acct = dn*bflo(ust); }
  else      { acc0 = 0.f; acc1 = 0.f; acct = 0.f; }
  int rb = rowptr[n], re = rowptr[n+1];
  int j = rb;
  for(; j+8 <= re; j += 8){
    uint2 prA = s_srcw[j + g];
    uint2 prB = s_srcw[j + 4 + g];
    float geA = __uint_as_float(prA.y);
    float geB = __uint_as_float(prB.y);
    const u32* rA = hb + (size_t)prA.x*17;
    const u32* rB = hb + (size_t)prB.x*17;
    u32 uA  = rA[l], uB = rB[l];
    u32 utA = t0 ? rA[16] : 0u;
    u32 utB = t0 ? rB[16] : 0u;
    acc0 = fmaf(geA, bflo(uA),  fmaf(geB, bflo(uB),  acc0));
    acc1 = fmaf(geA, bfhi(uA),  fmaf(geB, bfhi(uB),  acc1));
    acct = fmaf(geA, bflo(utA), fmaf(geB, bflo(utB), acct));
  }
  if(j+4 <= re){
    uint2 pr = s_srcw[j + g];
    float ge = __uint_as_float(pr.y);
    const u32* r = hb + (size_t)pr.x*17;
    u32 u  = r[l];
    u32 ut = t0 ? r[16] : 0u;
    acc0 = fmaf(ge, bflo(u),  acc0);
    acc1 = fmaf(ge, bfhi(u),  acc1);
    acct = fmaf(ge, bflo(ut), acct);
    j += 4;
  }
  int rem = re - j;
  if(rem > 0){
    bool val = (g < rem);
    uint2 pr = s_srcw[val ? (j + g) : j];
    float ge = val ? __uint_as_float(pr.y) : 0.f;
    const u32* r = hb + (size_t)pr.x*17;
    u32 u  = r[l];
    u32 ut = t0 ? r[16] : 0u;
    acc0 = fmaf(ge, bflo(u),  acc0);
    acc1 = fmaf(ge, bfhi(u),  acc1);
    acct = fmaf(ge, bflo(ut), acct);
  }
  #pragma unroll
  for(int m=16;m<=32;m<<=1){
    acc0 += __shfl_xor(acc0, m, 64);
    acc1 += __shfl_xor(acc1, m, 64);
    acct += __shfl_xor(acct, m, 64);
  }
  if(g == 0){
    int c0 = 2*l, c1 = 2*l+1;
    float v0 = fmaxf(dn*acc0 + gcnb[c0], 0.f);
    float v1 = fmaxf(dn*acc1 + gcnb[c1], 0.f);
    float i0 = bnw[c0] / sqrtf(bnv[c0] + BN_EPS);
    float i1 = bnw[c1] / sqrtf(bnv[c1] + BN_EPS);
    float2 o;
    o.x = v0*i0 + (bnb[c0] - bnm[c0]*i0);
    o.y = v1*i1 + (bnb[c1] - bnm[c1]*i1);
    ((float2*)(xp1 + (size_t)n*36))[l] = o;
    if(t0){
      float vt = fmaxf(dn*acct + gcnb[32], 0.f);
      float it = bnw[32] / sqrtf(bnv[32] + BN_EPS);
      float2 ot; ot.x = vt*it + (bnb[32] - bnm[32]*it); ot.y = 0.f;
      ((float2*)(xp1 + (size_t)n*36))[16] = ot;
      float2 z; z.x = 0.f; z.y = 0.f;
      ((float2*)(xp1 + (size_t)n*36))[17] = z;
    }
  }
}

// ---------------- GATv2 ----------------
// xlb row layout (stride 72 u32): per head h at h*36: slots 0..31 = ch 0..63
// (fp16 pairs), slot 32 = ch 64,65 (fp16), slot 33 = fp32 bits of slope/ln2*dotL,
// slots 34,35 pad (16B alignment for uint4 reads of both heads).
// dotL[n,h] = sum_c att[h,c]*xl[n,h,c] = (sum_c att[h,c]*WL[h,c,:]) . x[n]
//           = u[h] . x[n]  -- u precontracted per block (no atomics).
__global__ __launch_bounds__(320) void k_gatlin(const float* __restrict__ xp1, const float* __restrict__ wl,
                                                const float* __restrict__ wr, const float* __restrict__ att,
                                                u32* __restrict__ xlb, float* __restrict__ xr){
  __shared__ float sx[64*36];
  __shared__ float swle[66*33];
  __shared__ float swlo[66*33];
  __shared__ float swre[66*33];
  __shared__ float swro[66*33];
  __shared__ float su[2][33];
  int t = threadIdx.x;
  int n0 = blockIdx.x*64;
  int nn = N_NODES - n0; if(nn > 64) nn = 64;
  for(int i=t;i<2178;i+=320){
    int d = i/33, k = i - d*33;
    int gb = d*66 + k;
    swle[i] = wl[gb];
    swlo[i] = wl[gb+33];
    swre[i] = wr[gb];
    swro[i] = wr[gb+33];
  }
  int xcnt = nn*36;
  for(int i=t;i<xcnt;i+=320) sx[i] = xp1[(size_t)n0*36 + i];
  __syncthreads();
  // precontract u[h][k] = sum_dd att[h,2dd]*swle[(h*33+dd)*33+k] + att[h,2dd+1]*swlo[...]
  if(t < 66){
    int hh = (t >= 33) ? 1 : 0;
    int k = t - 33*hh;
    float s = 0.f;
    const float* ah = att + hh*66;
    #pragma unroll 3
    for(int dd=0;dd<33;dd++){
      int p = hh*33 + dd;
      s = fmaf(ah[2*dd],   swle[p*33+k], s);
      s = fmaf(ah[2*dd+1], swlo[p*33+k], s);
    }
    su[hh][k] = s;
  }
  if(t < 264){
    int ng = t/66, p = t - ng*66;
    int nbase = ng*16;
    float al0[16], al1[16], ar0[16], ar1[16];
    #pragma unroll
    for(int i=0;i<16;i++){ al0[i]=0.f; al1[i]=0.f; ar0[i]=0.f; ar1[i]=0.f; }
    const float* wle = swle + p*33;
    const float* wlo = swlo + p*33;
    const float* wre = swre + p*33;
    const float* wro = swro + p*33;
    for(int k=0;k<33;k++){
      float w0 = wle[k], w1 = wlo[k], w2 = wre[k], w3 = wro[k];
      const float* xcol = sx + nbase*36 + k;
      #pragma unroll
      for(int i=0;i<16;i++){
        float x = xcol[i*36];
        al0[i] = fmaf(x, w0, al0[i]);
        al1[i] = fmaf(x, w1, al1[i]);
        ar0[i] = fmaf(x, w2, ar0[i]);
        ar1[i] = fmaf(x, w3, ar1[i]);
      }
    }
    int head = (p >= 33) ? 1 : 0;
    int dd = p - 33*head;
    #pragma unroll
    for(int i=0;i<16;i++){
      int n = nbase + i;
      if(n < nn){
        size_t nidx = (size_t)(n0 + n);
        xlb[nidx*72 + head*36 + dd] = packh(al0[i], al1[i]);
        float2 v; v.x = ar0[i]; v.y = ar1[i];
        ((float2*)xr)[nidx*66 + p] = v;
      }
    }
  }
  __syncthreads();
  if(t < 128){
    int nl = t >> 1, hh = t & 1;
    if(nl < nn){
      const float* xv = sx + nl*36;
      float s = 0.f;
      #pragma unroll
      for(int k=0;k<33;k++) s = fmaf(su[hh][k], xv[k], s);
      xlb[(size_t)(n0 + nl)*72 + hh*36 + 33] =
        __float_as_uint(s * (LRELU_SLOPE*1.44269504089f));
    }
  }
}

// One block/node, 2 head-waves; wave = 8 x 8-lane groups; 8 edges in flight.
// Score decomposition: e/ln2 = sum_c att*(1-s)/ln2 * max(z,0) + s/ln2*(dotL[src]+dotR[dst]);
// dotR[dst] is per-destination-constant and cancels in the softmax, so dropped.
// Score path in fp16 packed math; DEPTH-2 SOFTWARE PIPELINE: the next 8-edge
// group's row loads are issued before the current group's score/accumulate,
// hiding one compute body of the random-gather latency per iteration.
__global__ __launch_bounds__(128) void k_gat(const int* __restrict__ rowptr, const u32* __restrict__ srcx,
                                             const u32* __restrict__ xlb, const float* __restrict__ xr,
                                             const float* __restrict__ att, const float* __restrict__ gatb,
                                             float* __restrict__ xp2){
  const float ATT_SC = (1.f - LRELU_SLOPE) * 1.44269504089f;
  int n = blockIdx.x;
  int h = threadIdx.x >> 6;
  int lane = threadIdx.x & 63;
  int l8 = lane & 7, g8 = lane >> 3;
  bool t0 = (l8 == 0);
  bool g0 = (g8 == 0);
  // xr: channels 8*l8 .. 8*l8+7 of head h (per-node constants), packed to fp16
  const float* xrp = xr + (size_t)n*132 + h*66 + 8*l8;
  float2 x01 = ((const float2*)xrp)[0];
  float2 x23 = ((const float2*)xrp)[1];
  float2 x45 = ((const float2*)xrp)[2];
  float2 x67 = ((const float2*)xrp)[3];
  float2 xt  = t0 ? *(const float2*)(xr + (size_t)n*132 + h*66 + 64) : make_float2(0.f,0.f);
  u32 xh0 = packh(x01.x, x01.y);
  u32 xh1 = packh(x23.x, x23.y);
  u32 xh2 = packh(x45.x, x45.y);
  u32 xh3 = packh(x67.x, x67.y);
  u32 xht = t0 ? packh(xt.x, xt.y) : 0u;
  const float* ap = att + h*66 + 8*l8;
  float2 a01 = ((const float2*)ap)[0];
  float2 a23 = ((const float2*)ap)[1];
  float2 a45 = ((const float2*)ap)[2];
  float2 a67 = ((const float2*)ap)[3];
  float2 atl = *(const float2*)(att + h*66 + 64);
  u32 ah0 = packh(a01.x*ATT_SC, a01.y*ATT_SC);
  u32 ah1 = packh(a23.x*ATT_SC, a23.y*ATT_SC);
  u32 ah2 = packh(a45.x*ATT_SC, a45.y*ATT_SC);
  u32 ah3 = packh(a67.x*ATT_SC, a67.y*ATT_SC);
  u32 aht = packh(atl.x*ATT_SC, atl.y*ATT_SC);

  const u32* xbase = xlb + h*36;
  float v0,v1,v2,v3,v4,v5,v6,v7,w0,w1;

// dual accumulators (3+3 serial dot2s instead of 5) shorten the score chain
#define GSCORE(U, TU, P) { \
  u32 q0 = pkmax0(pkadd(U.x, xh0)); \
  u32 q1 = pkmax0(pkadd(U.y, xh1)); \
  u32 q2 = pkmax0(pkadd(U.z, xh2)); \
  u32 q3 = pkmax0(pkadd(U.w, xh3)); \
  u32 qt = pkmax0(pkadd(TU.x, xht)); \
  float pA = __uint_as_float(TU.y); \
  float pB = 0.f; \
  pA = dot2(q0, ah0, pA); \
  pB = dot2(q1, ah1, pB); \
  pA = dot2(q2, ah2, pA); \
  pB = dot2(q3, ah3, pB); \
  pB = dot2(qt, aht, pB); \
  v0 = hlo(U.x); v1 = hhi(U.x); \
  v2 = hlo(U.y); v3 = hhi(U.y); \
  v4 = hlo(U.z); v5 = hhi(U.z); \
  v6 = hlo(U.w); v7 = hhi(U.w); \
  w0 = hlo(TU.x); w1 = hhi(TU.x); \
  P = red8(pA + pB); }

  // self score (all 8 groups compute identically -> all lanes get p_self)
  const u32* srow = xbase + (size_t)n*72;
  uint4 su = ((const uint4*)srow)[l8];
  uint2 stl = t0 ? ((const uint2*)srow)[16] : make_uint2(0u,0u);
  float ps;
  GSCORE(su, stl, ps);
  float cn = -ps;
  // seed accumulators with self contribution (weight exp2(0)=1) on group 0
  float A0 = g0? v0 : 0.f, A1 = g0? v1 : 0.f, A2 = g0? v2 : 0.f, A3 = g0? v3 : 0.f;
  float A4 = g0? v4 : 0.f, A5 = g0? v5 : 0.f, A6 = g0? v6 : 0.f, A7 = g0? v7 : 0.f;
  float T0 = g0? w0 : 0.f, T1 = g0? w1 : 0.f;
  float asum = g0 ? 1.f : 0.f;

  int rb = rowptr[n], re = rowptr[n+1];
  int j = rb;
  int nfull = (re - rb) >> 3;
  // ---- depth-2 pipeline: prefetch group 0 ----
  uint4 u_n = make_uint4(0u,0u,0u,0u);
  uint2 tu_n = make_uint2(0u,0u);
  if(nfull > 0){
    int s = (int)srcx[2*(j + g8)];
    const u32* r = xbase + (size_t)s*72;
    u_n = ((const uint4*)r)[l8];
    if(t0) tu_n = ((const uint2*)r)[16];
  }
  for(int it=0; it<nfull; ++it){
    uint4 u = u_n; uint2 tu = tu_n;
    if(it+1 < nfull){
      int s2 = (int)srcx[2*(j + 8 + g8)];
      const u32* r2 = xbase + (size_t)s2*72;
      u_n = ((const uint4*)r2)[l8];
      if(t0) tu_n = ((const uint2*)r2)[16];
      else   tu_n = make_uint2(0u,0u);
    }
    float p;
    GSCORE(u, tu, p);
    float a = __builtin_amdgcn_exp2f(p + cn);
    A0 = fmaf(a, v0, A0); A1 = fmaf(a, v1, A1); A2 = fmaf(a, v2, A2); A3 = fmaf(a, v3, A3);
    A4 = fmaf(a, v4, A4); A5 = fmaf(a, v5, A5); A6 = fmaf(a, v6, A6); A7 = fmaf(a, v7, A7);
    T0 = fmaf(a, w0, T0); T1 = fmaf(a, w1, T1);
    asum += a;
    j += 8;
  }
  int rem = re - j;
  if(rem > 0){
    bool val = (g8 < rem);
    int s = val ? (int)srcx[2*(j + g8)] : n;
    const u32* r = xbase + (size_t)s*72;
    uint4 u = ((const uint4*)r)[l8];
    uint2 tu = t0 ? ((const uint2*)r)[16] : make_uint2(0u,0u);
    float p;
    GSCORE(u, tu, p);
    float a = val ? __builtin_amdgcn_exp2f(p + cn) : 0.f;
    A0 = fmaf(a, v0, A0); A1 = fmaf(a, v1, A1); A2 = fmaf(a, v2, A2); A3 = fmaf(a, v3, A3);
    A4 = fmaf(a, v4, A4); A5 = fmaf(a, v5, A5); A6 = fmaf(a, v6, A6); A7 = fmaf(a, v7, A7);
    T0 = fmaf(a, w0, T0); T1 = fmaf(a, w1, T1);
    asum += a;
  }
#undef GSCORE

  A0 = redall(A0); A1 = redall(A1); A2 = redall(A2); A3 = redall(A3);
  A4 = redall(A4); A5 = redall(A5); A6 = redall(A6); A7 = redall(A7);
  T0 = redall(T0); T1 = redall(T1);
  asum = redall(asum);

  if(g0){
    float inv = 1.f / asum;
    const float* gp = gatb + h*66 + 8*l8;
    float2 g01 = ((const float2*)gp)[0];
    float2 g23 = ((const float2*)gp)[1];
    float2 g45 = ((const float2*)gp)[2];
    float2 g67 = ((const float2*)gp)[3];
    float* op = xp2 + (size_t)n*132 + h*66 + 8*l8;
    float2 o;
    o.x = fmaxf(fmaf(A0,inv,g01.x),0.f); o.y = fmaxf(fmaf(A1,inv,g01.y),0.f); ((float2*)op)[0] = o;
    o.x = fmaxf(fmaf(A2,inv,g23.x),0.f); o.y = fmaxf(fmaf(A3,inv,g23.y),0.f); ((float2*)op)[1] = o;
    o.x = fmaxf(fmaf(A4,inv,g45.x),0.f); o.y = fmaxf(fmaf(A5,inv,g45.y),0.f); ((float2*)op)[2] = o;
    o.x = fmaxf(fmaf(A6,inv,g67.x),0.f); o.y = fmaxf(fmaf(A7,inv,g67.y),0.f); ((float2*)op)[3] = o;
    if(t0){
      float2 gt = *(const float2*)(gatb + h*66 + 64);
      float2 ot;
      ot.x = fmaxf(fmaf(T0,inv,gt.x),0.f); ot.y = fmaxf(fmaf(T1,inv,gt.y),0.f);
      *(float2*)(xp2 + (size_t)n*132 + h*66 + 64) = ot;
    }
  }
}

// ---------------- pooling + MLP head ----------------
__global__ __launch_bounds__(256) void k_bounds(const int* __restrict__ batch, int* __restrict__ gstart,
                                                int* __restrict__ gend){
  int n = blockIdx.x*256 + threadIdx.x;
  if(n >= N_NODES) return;
  int b = batch[n];
  if(n == 0) gstart[b] = 0;
  else {
    int p = batch[n-1];
    if(p != b){ gstart[b] = n; gend[p] = n; }
  }
  if(n == N_NODES-1) gend[b] = N_NODES;
}

__global__ __launch_bounds__(128) void k_poolp(const float* __restrict__ xp2, const int* __restrict__ gstart,
                                               const int* __restrict__ gend, float* __restrict__ pp){
  int g = blockIdx.x, seg = blockIdx.y, t = threadIdx.x;
  int s = gstart[g], e = gend[g];
  int len = e - s; if(len < 0) len = 0;
  int ns = s + (int)(((long long)len*seg)>>4);
  int ne = s + (int)(((long long)len*(seg+1))>>4);
  float a0 = 0.f, a1 = 0.f;
  for(int n=ns;n<ne;n++){
    a0 += xp2[(size_t)n*132 + t];
    if(t < 4) a1 += xp2[(size_t)n*132 + 128 + t];
  }
  float* o = pp + (size_t)(g*16 + seg)*132;
  o[t] = a0;
  if(t < 4) o[128 + t] = a1;
}

__global__ __launch_bounds__(256) void k_pfc1(const float* __restrict__ pp, const int* __restrict__ gstart,
                                              const int* __restrict__ gend, const float* __restrict__ w,
                                              const float* __restrict__ b, float* __restrict__ h1T){
  __shared__ float pooled[132];
  int g = blockIdx.x, t = threadIdx.x;
  if(t < 132){
    float s = 0.f;
    #pragma unroll
    for(int k=0;k<16;k++) s += pp[(size_t)(g*16 + k)*132 + t];
    int c = gend[g] - gstart[g]; if(c < 1) c = 1;
    pooled[t] = s/(float)c;
  }
  __syncthreads();
  #pragma unroll
  for(int r=0;r<4;r++){
    int o = r*256 + t;
    const float* wr = w + o*132;
    float acc = b[o];
    for(int k=0;k<132;k++) acc = fmaf(pooled[k], wr[k], acc);
    h1T[o*64+g] = fmaxf(acc, 0.f);
  }
}

__global__ __launch_bounds__(256) void k_fc2(const float* __restrict__ h1T, const float* __restrict__ w,
                                             const float* __restrict__ b, float* __restrict__ out){
  __shared__ float part[256];
  int o = blockIdx.x, t = threadIdx.x;
  int s = t >> 6, g = t & 63;
  const float* wr = w + o*1024 + s*256;
  const float* hp = h1T + (size_t)(s*256)*64 + g;
  float acc = 0.f;
  for(int k=0;k<256;k++) acc = fmaf(hp[k*64], wr[k], acc);
  part[t] = acc;
  __syncthreads();
  if(s == 0){
    float r = b[o] + part[g] + part[64+g] + part[128+g] + part[192+g];
    out[8192 + g*128 + o] = r;
  }
}

// ---------------- RNA branches ----------------
__global__ __launch_bounds__(256) void k_bucket(const int* __restrict__ g, int L, int V,
                                                int* __restrict__ sci, int* __restrict__ off){
  __shared__ int gl[3000];
  __shared__ int hist[65];
  __shared__ int base[66];
  int b = blockIdx.x, t = threadIdx.x;
  if(t < V) hist[t] = 0;
  for(int i=t;i<L;i+=256) gl[i] = g[b*L + i];
  __syncthreads();
  for(int i=t;i<L;i+=256) atomicAdd(&hist[gl[i]], 1);
  __syncthreads();
  if(t == 0){
    int run = 0;
    for(int v=0;v<V;v++){ base[v] = run; run += hist[v]; }
    base[V] = run;
  }
  __syncthreads();
  if(t <= V) off[b*(V+1) + t] = base[t];
  if(t < V) hist[t] = 0;
  __syncthreads();
  for(int i=t;i<L;i+=256){
    int v = gl[i];
    int p = base[v] + atomicAdd(&hist[v], 1);
    sci[b*3000 + p] = i*8;
  }
}

__global__ __launch_bounds__(256) void k_sgather(const int* __restrict__ sci, const int* __restrict__ off,
                                                 const float* __restrict__ w, int V, int wstride,
                                                 int sstride, float* __restrict__ S){
  __shared__ int loff[66];
  __shared__ int lci[3000];
  int b = blockIdx.x, q = blockIdx.y, t = threadIdx.x;
  int nsplit = gridDim.y;
  if(t <= V) loff[t] = off[b*(V+1) + t];
  __syncthreads();
  int vs = (V*q)/nsplit, ve = (V*(q+1))/nsplit;
  if(vs == ve) return;
  int p0 = loff[vs], p1 = loff[ve];
  for(int i=p0+t;i<p1;i+=256) lci[i-p0] = sci[b*3000 + i];
  __syncthreads();
  int co = t >> 3, kk = t & 7;
  const float* wrow = w + co*wstride + kk;
  float* Srow = S + (size_t)b*32*sstride + co*sstride + kk;
  for(int v=vs;v<ve;v++){
    int j = loff[v] - p0, je = loff[v+1] - p0;
    float a0=0.f,a1=0.f,a2=0.f,a3=0.f,a4=0.f,a5=0.f,a6=0.f,a7=0.f;
    for(; j+8 <= je; j += 8){
      a0 += wrow[lci[j]];
      a1 += wrow[lci[j+1]];
      a2 += wrow[lci[j+2]];
      a3 += wrow[lci[j+3]];
      a4 += wrow[lci[j+4]];
      a5 += wrow[lci[j+5]];
      a6 += wrow[lci[j+6]];
      a7 += wrow[lci[j+7]];
    }
    for(; j<je; j++) a0 += wrow[lci[j]];
    Srow[v*8] = ((a0+a1)+(a2+a3)) + ((a4+a5)+(a6+a7));
  }
}

__global__ __launch_bounds__(128) void k_y(const float* __restrict__ S1, const float* __restrict__ S2,
                                           const float* __restrict__ emb1, const float* __restrict__ emb2,
                                           const float* __restrict__ c1b, const float* __restrict__ c2b,
                                           float* __restrict__ ysum){
  __shared__ float em1[640];
  __shared__ float em2[8320];
  __shared__ float Sa[320];
  __shared__ float Sb[4160];
  int b = blockIdx.x, cg = blockIdx.y, t = threadIdx.x;
  for(int i=t;i<640;i+=128)  em1[i] = emb1[i];
  for(int i=t;i<8320;i+=128) em2[i] = emb2[i];
  for(int i=t;i<320;i+=128)  Sa[i] = S1[b*1280 + cg*320 + i];
  for(int i=t;i<4160;i+=128) Sb[i] = S2[(size_t)b*16640 + cg*4160 + i];
  __syncthreads();
  if(t >= 121) return;
  #pragma unroll
  for(int c8=0;c8<8;c8++){
    int co = cg*8 + c8;
    const float* sa = Sa + c8*40;
    float acc1 = c1b[co];
    #pragma unroll
    for(int v=0;v<5;v++)
      #pragma unroll
      for(int k=0;k<8;k++) acc1 = fmaf(sa[v*8+k], em1[v*128 + t + k], acc1);
    const float* sb = Sb + c8*520;
    float acc2 = c2b[co];
    for(int v=0;v<65;v++){
      #pragma unroll
      for(int k=0;k<8;k++) acc2 = fmaf(sb[v*8+k], em2[v*128 + t + k], acc2);
    }
    ysum[b*3872 + co*121 + t] = 0.5f*(acc1 + acc2);
  }
}

__global__ __launch_bounds__(256) void k_fcxr(const float* __restrict__ ysum, const float* __restrict__ fcw,
                                              const float* __restrict__ fcb, float* __restrict__ out){
  __shared__ float part[512];
  int bp = blockIdx.x, q = blockIdx.y, t = threadIdx.x;
  int b0 = bp*2;
  int ol = t >> 3;
  int o  = q*32 + ol;
  int slice = t & 7;
  const float4* ys0 = (const float4*)(ysum + b0*3872) + slice*121;
  const float4* ys1 = (const float4*)(ysum + (b0+1)*3872) + slice*121;
  const float4* wr  = (const float4*)(fcw + (size_t)o*3872) + slice*121;
  float acc0 = 0.f, acc1 = 0.f;
  for(int k=0;k<121;k++){
    float4 w4 = wr[k];
    float4 y0 = ys0[k], y1 = ys1[k];
    acc0 += y0.x*w4.x + y0.y*w4.y + y0.z*w4.z + y0.w*w4.w;
    acc1 += y1.x*w4.x + y1.y*w4.y + y1.z*w4.z + y1.w*w4.w;
  }
  part[t] = acc0;
  part[256+t] = acc1;
  __syncthreads();
  if(slice == 0){
    float s0 = fcb[o], s1 = fcb[o];
    #pragma unroll
    for(int i=0;i<8;i++){ s0 += part[ol*8 + i]; s1 += part[256 + ol*8 + i]; }
    out[b0*128 + o] = s0;
    out[(b0+1)*128 + o] = s1;
  }
}

extern "C" void kernel_launch(void* const* d_in, const int* in_sizes, int n_in,
                              void* d_out, int out_size, void* d_ws, size_t ws_size,
                              hipStream_t stream){
  const int*   g_rna = (const int*)  d_in[0];
  const int*   l_rna = (const int*)  d_in[1];
  const float* pro_x = (const float*)d_in[2];
  const int*   eidx  = (const int*)  d_in[3];
  const float* pro_w = (const float*)d_in[4];
  const int*   batch = (const int*)  d_in[5];
  const float* emb1  = (const float*)d_in[6];
  const float* emb2  = (const float*)d_in[7];
  const float* c1w   = (const float*)d_in[8];
  const float* c1b   = (const float*)d_in[9];
  const float* c2w   = (const float*)d_in[10];
  const float* c2b   = (const float*)d_in[11];
  const float* fcxw  = (const float*)d_in[12];
  const float* fcxb  = (const float*)d_in[13];
  const float* gcnw  = (const float*)d_in[14];
  const float* gcnb  = (const float*)d_in[15];
  const float* bnm   = (const float*)d_in[16];
  const float* bnv   = (const float*)d_in[17];
  const float* bnw   = (const float*)d_in[18];
  const float* bnb   = (const float*)d_in[19];
  const float* gwl   = (const float*)d_in[20];
  const float* gwr   = (const float*)d_in[21];
  const float* gatt  = (const float*)d_in[22];
  const float* gatb  = (const float*)d_in[23];
  const float* f1w   = (const float*)d_in[24];
  const float* f1b   = (const float*)d_in[25];
  const float* f2w   = (const float*)d_in[26];
  const float* f2b_  = (const float*)d_in[27];
  float* out = (float*)d_out;

  char* ws = (char*)d_ws;
  size_t off = 0;
  auto A = [&](size_t n)->char*{ char* p = ws + off; off = (off + n + 255) & ~(size_t)255; return p; };
  u64*   pk     = (u64*)  A((size_t)N_NODES*8);
  int*   fill   = (int*)  A((size_t)N_NODES*4);
  int*   bcnt   = (int*)  A((size_t)NBUCK*4);
  size_t zero_bytes = off;
  int*   rowptr = (int*)  A((size_t)(N_NODES+1)*4);
  int*   bsum   = (int*)  A(196*4);
  int*   bbase  = (int*)  A(196*4);
  uint2* s_srcw = (uint2*)A((size_t)N_EDGES*8);
  u32*   hb     = (u32*)  A((size_t)N_NODES*17*4);
  float* xp1    = (float*)A((size_t)N_NODES*36*4);
  u32*   xlb    = (u32*)  A((size_t)N_NODES*72*4);
  float* xr     = (float*)A((size_t)N_NODES*132*4);
  float* xp2    = (float*)A((size_t)N_NODES*132*4);
  int*   gstart = (int*)  A(64*4);
  int*   gend   = (int*)  A(64*4);
  float* pp     = (float*)A((size_t)64*16*132*4);
  float* h1T    = (float*)A(1024*64*4);
  float* S1     = (float*)A((size_t)64*1280*4);
  float* S2     = (float*)A((size_t)64*16640*4);
  float* ysum   = (float*)A((size_t)64*3872*4);
  int*   sci1   = (int*)  A((size_t)64*3000*4);
  int*   off1   = (int*)  A((size_t)64*8*4);
  int*   sci2   = (int*)  A((size_t)64*3000*4);
  int*   off2   = (int*)  A((size_t)64*66*4);
  (void)ws_size; (void)in_sizes; (void)n_in; (void)out_size;

  // ebuf (12.8 MB, uint2 records) aliases xr (26.4 MB): dead until k_gatlin,
  // and the CSR build completes (stream-ordered) before k_gatlin writes xr.
  uint2* ebuf = (uint2*)xr;

  hipMemsetAsync(ws, 0, zero_bytes, stream);

  // protein GNN pipeline
  k_hist   <<<3125, 256, 0, stream>>>(eidx, pro_w, pk);
  k_scan1  <<<196, 256, 0, stream>>>(pk, rowptr, bsum);
  k_scan2  <<<1, 256, 0, stream>>>(bsum, bbase, rowptr, gstart, gend);
  k_scan3  <<<196, 256, 0, stream>>>(rowptr, bbase);
  k_bin    <<<NBLKBIN, 256, 0, stream>>>(eidx, pro_w, pk, rowptr, fill, bcnt, ebuf, s_srcw);
  k_place  <<<NBUCK, 256, 0, stream>>>(bcnt, ebuf, rowptr, s_srcw);
  k_h      <<<196, 256, 0, stream>>>(pro_x, gcnw, hb);
  k_gcn    <<<12500, 256, 0, stream>>>(hb, rowptr, s_srcw, pk, gcnb, bnm, bnv, bnw, bnb, xp1);
  k_gatlin <<<782, 320, 0, stream>>>(xp1, gwl, gwr, gatt, xlb, xr);
  k_gat    <<<N_NODES, 128, 0, stream>>>(rowptr, (const u32*)s_srcw, xlb, xr, gatt, gatb, xp2);
  k_bounds <<<196, 256, 0, stream>>>(batch, gstart, gend);
  k_poolp  <<<dim3(64,16), 128, 0, stream>>>(xp2, gstart, gend, pp);
  k_pfc1   <<<64, 256, 0, stream>>>(pp, gstart, gend, f1w, f1b, h1T);
  k_fc2    <<<128, 256, 0, stream>>>(h1T, f2w, f2b_, out);

  // RNA branches
  k_bucket <<<64, 256, 0, stream>>>(g_rna, 3000, 5, sci1, off1);
  k_bucket <<<64, 256, 0, stream>>>(l_rna, 2998, 65, sci2, off2);
  k_sgather<<<dim3(64,5), 256, 0, stream>>>(sci1, off1, c1w, 5, 24000, 40, S1);
  k_sgather<<<dim3(64,32), 256, 0, stream>>>(sci2, off2, c2w, 65, 23984, 520, S2);
  k_y      <<<dim3(64,4), 128, 0, stream>>>(S1, S2, emb1, emb2, c1b, c2b, ysum);
  k_fcxr   <<<dim3(32,4), 256, 0, stream>>>(ysum, fcxw, fcxb, out);
}

// Round 8
// 524.381 us; speedup vs baseline: 1.0446x; 1.0425x over previous
//
#include <hip/hip_runtime.h>

#define N_NODES 50000
#define N_EDGES 800000
#define LRELU_SLOPE 0.2f
#define BN_EPS 1e-5f

#define BSHIFT 7
#define NBUCK 391            // ceil(50000/128)
#define BCAP 4096            // mean 2048/bucket; overflow falls back (correct for any dist)
#define EPB 4096             // edges per k_bin block
#define NBLKBIN ((N_EDGES + EPB - 1)/EPB)

typedef unsigned int u32;
typedef unsigned long long u64;

__device__ __forceinline__ float lrelu(float x){ return fmaxf(x,0.f) + LRELU_SLOPE*fminf(x,0.f); }
__device__ __forceinline__ float bflo(u32 u){ return __uint_as_float(u<<16); }
__device__ __forceinline__ float bfhi(u32 u){ return __uint_as_float(u & 0xffff0000u); }
__device__ __forceinline__ u32 packbf(float a, float b){
  u32 ua = __float_as_uint(a); ua = (ua + 0x7fffu + ((ua>>16)&1u)) >> 16;
  u32 ub = __float_as_uint(b); ub = (ub + 0x7fffu + ((ub>>16)&1u)) >> 16;
  return ua | (ub<<16);
}

// fp16 pair in a u32 -- no hip_fp16.h API (header lacks __hmax2 on this ROCm).
typedef _Float16 h2v __attribute__((ext_vector_type(2)));
union uhcv { u32 i; h2v h; };
__device__ __forceinline__ u32 packh(float a, float b){
  uhcv c; c.h.x = (_Float16)a; c.h.y = (_Float16)b; return c.i;
}
__device__ __forceinline__ float hlo(u32 u){ uhcv c; c.i = u; return (float)c.h.x; }
__device__ __forceinline__ float hhi(u32 u){ uhcv c; c.i = u; return (float)c.h.y; }
__device__ __forceinline__ h2v toh2(u32 u){ uhcv c; c.i = u; return c.h; }
// packed fp16 ops via asm (VOP3P, baseline gfx9+)
__device__ __forceinline__ u32 pkadd(u32 a, u32 b){
  u32 r; asm("v_pk_add_f16 %0, %1, %2" : "=v"(r) : "v"(a), "v"(b)); return r;
}
__device__ __forceinline__ u32 pkmax0(u32 a){
  u32 r; asm("v_pk_max_f16 %0, %1, %2" : "=v"(r) : "v"(a), "v"(0u)); return r;
}
__device__ __forceinline__ float dot2(u32 a, u32 b, float c){
#if defined(__has_builtin) && __has_builtin(__builtin_amdgcn_fdot2)
  return __builtin_amdgcn_fdot2(toh2(a), toh2(b), c, false);
#else
  float r; asm("v_dot2_f32_f16 %0, %1, %2, %3" : "=v"(r) : "v"(a), "v"(b), "v"(c)); return r;
#endif
}

// packed (cnt<<40 | deg in 2^-26 fixed point)
__device__ __forceinline__ float degof(u64 p){
  return (float)(p & 0xFFFFFFFFFFull) * (1.0f/67108864.0f);
}

// DPP-fused adds: VALU-only lane reduction (no ds_swizzle).
template<int CTRL>
__device__ __forceinline__ float dppadd(float x){
  int y = __builtin_amdgcn_update_dpp(0, __float_as_int(x), CTRL, 0xF, 0xF, false);
  return x + __int_as_float(y);
}
// sum over 8-lane group (lanes differing in bits 0..2)
__device__ __forceinline__ float red8(float p){
  p = dppadd<0x141>(p);  // row_half_mirror: reverse within 8
  p = dppadd<0x4E>(p);   // quad_perm [2,3,0,1] = xor2
  p = dppadd<0xB1>(p);   // quad_perm [1,0,3,2] = xor1
  return p;
}
// sum across the 8 groups (lane bits 3,4,5), keeping l8 lanes separate
__device__ __forceinline__ float redall(float v){
  v = dppadd<0x128>(v);          // row_ror:8 == xor8 within 16-lane row
  v += __shfl_xor(v, 16, 64);
  v += __shfl_xor(v, 32, 64);
  return v;
}

// ---------------- fused input-only kernels: hist + h + bucket(g) + bucket(l) ----------------
__device__ void bucket_body(const int* __restrict__ g, int L, int V,
                            int* __restrict__ sci, int* __restrict__ off,
                            int* shm, int b, int t){
  int* gl   = shm;        // [3000]
  int* hist = shm + 3000; // [65]
  int* base = shm + 3065; // [66]
  if(t < V) hist[t] = 0;
  for(int i=t;i<L;i+=256) gl[i] = g[b*L + i];
  __syncthreads();
  for(int i=t;i<L;i+=256) atomicAdd(&hist[gl[i]], 1);
  __syncthreads();
  if(t == 0){
    int run = 0;
    for(int v=0;v<V;v++){ base[v] = run; run += hist[v]; }
    base[V] = run;
  }
  __syncthreads();
  if(t <= V) off[b*(V+1) + t] = base[t];
  if(t < V) hist[t] = 0;
  __syncthreads();
  for(int i=t;i<L;i+=256){
    int v = gl[i];
    int p = base[v] + atomicAdd(&hist[v], 1);
    sci[b*3000 + p] = i*8;
  }
}

__global__ __launch_bounds__(256) void k_pre(const int* __restrict__ eidx, const float* __restrict__ pw,
                                             u64* __restrict__ pk,
                                             const float* __restrict__ px, const float* __restrict__ gw,
                                             u32* __restrict__ hb,
                                             const int* __restrict__ grna, const int* __restrict__ lrna,
                                             int* __restrict__ sci1, int* __restrict__ off1,
                                             int* __restrict__ sci2, int* __restrict__ off2){
  __shared__ int shm[3131];
  int b = blockIdx.x, t = threadIdx.x;
  if(b < 3125){
    // k_hist region (3125*256 == N_EDGES exactly)
    int e = b*256 + t;
    int d = eidx[N_EDGES + e];
    u64 q = (u64)(pw[e] * 67108864.f);
    atomicAdd(&pk[d], (1ull<<40) | q);
    return;
  }
  b -= 3125;
  if(b < 196){
    // k_h region
    int n = b*256 + t;
    if(n >= N_NODES) return;
    float x[33];
    #pragma unroll
    for(int k=0;k<33;k++) x[k] = px[n*33+k];
    float a[33];
    for(int c=0;c<33;c++){
      float s = 0.f;
      #pragma unroll
      for(int k=0;k<33;k++) s = fmaf(x[k], gw[c*33+k], s);
      a[c] = s;
    }
    #pragma unroll
    for(int d=0;d<16;d++) hb[(size_t)n*17 + d] = packbf(a[2*d], a[2*d+1]);
    hb[(size_t)n*17 + 16] = packbf(a[32], 0.f);
    return;
  }
  b -= 196;
  if(b < 64){ bucket_body(grna, 3000, 5, sci1, off1, shm, b, t); return; }
  b -= 64;
  bucket_body(lrna, 2998, 65, sci2, off2, shm, b, t);
}

// ---------------- CSR build ----------------
__global__ __launch_bounds__(256) void k_scan1(const u64* __restrict__ pk, int* __restrict__ rowptr,
                                               int* __restrict__ bsum){
  __shared__ int sc[256];
  int b = blockIdx.x, t = threadIdx.x;
  int i = b*256 + t;
  int v = (i < N_NODES) ? (int)(pk[i] >> 40) : 0;
  sc[t] = v;
  __syncthreads();
  for(int off=1; off<256; off<<=1){
    int x = (t>=off)? sc[t-off] : 0;
    __syncthreads();
    sc[t] += x;
    __syncthreads();
  }
  if(i < N_NODES) rowptr[i] = sc[t] - v;
  if(t == 255) bsum[b] = sc[255];
}

__global__ __launch_bounds__(256) void k_scan2(const int* __restrict__ bsum, int* __restrict__ bbase,
                                               int* __restrict__ rowptr, int* __restrict__ gstart,
                                               int* __restrict__ gend){
  __shared__ int sc[256];
  int t = threadIdx.x;
  int v = (t < 196) ? bsum[t] : 0;
  sc[t] = v;
  __syncthreads();
  for(int off=1; off<256; off<<=1){
    int x = (t>=off)? sc[t-off] : 0;
    __syncthreads();
    sc[t] += x;
    __syncthreads();
  }
  if(t < 196) bbase[t] = sc[t] - v;
  if(t == 255) rowptr[N_NODES] = sc[255];
  if(t < 64){ gstart[t] = N_NODES; gend[t] = 0; }
}

__global__ __launch_bounds__(256) void k_scan3(int* __restrict__ rowptr, const int* __restrict__ bbase){
  int b = blockIdx.x, t = threadIdx.x;
  int i = b*256 + t;
  if(i < N_NODES) rowptr[i] += bbase[b];
}

// Block-aggregated binning: per-edge work stays in LDS; global atomics only
// per (block,bucket). Output ebuf written coalesced in bucket-sorted runs.
__global__ __launch_bounds__(256) void k_bin(const int* __restrict__ eidx, const float* __restrict__ pw,
                                             const u64* __restrict__ pk, const int* __restrict__ rowptr,
                                             int* __restrict__ fill, int* __restrict__ bcnt,
                                             uint2* __restrict__ ebuf, uint2* __restrict__ s_srcw){
  __shared__ int hist[NBUCK];
  __shared__ int scn[NBUCK];
  __shared__ int gbs[NBUCK];
  __shared__ uint2 lbuf[EPB];
  __shared__ unsigned short sbkt[EPB];
  int t = threadIdx.x;
  int e0 = blockIdx.x*EPB;
  int ne = N_EDGES - e0; if(ne > EPB) ne = EPB;
  for(int i=t;i<NBUCK;i+=256) hist[i] = 0;
  __syncthreads();
  for(int i=t;i<ne;i+=256) atomicAdd(&hist[eidx[N_EDGES + e0 + i] >> BSHIFT], 1);
  __syncthreads();
  for(int i=t;i<NBUCK;i+=256) scn[i] = hist[i];
  __syncthreads();
  for(int off=1; off<NBUCK; off<<=1){
    int i0 = t, i1 = t + 256;
    int v0 = (i0 < NBUCK && i0 >= off) ? scn[i0-off] : 0;
    int v1 = (i1 < NBUCK && i1 >= off) ? scn[i1-off] : 0;
    __syncthreads();
    if(i0 < NBUCK) scn[i0] += v0;
    if(i1 < NBUCK) scn[i1] += v1;
    __syncthreads();
  }
  for(int i=t;i<NBUCK;i+=256){
    int c = hist[i];
    gbs[i] = c ? atomicAdd(&bcnt[i], c) : 0;
    scn[i] -= c;
    hist[i] = 0;
  }
  __syncthreads();
  for(int i=t;i<ne;i+=256){
    int e = e0 + i;
    int d = eidx[N_EDGES + e];
    int s = eidx[e];
    float ge = rsqrtf(degof(pk[s]) + 1.f) * pw[e];
    int b = d >> BSHIFT;
    int slot = scn[b] + atomicAdd(&hist[b], 1);
    uint2 r; r.x = (u32)s | ((u32)(d & ((1<<BSHIFT)-1)) << 17); r.y = __float_as_uint(ge);
    lbuf[slot] = r;
    sbkt[slot] = (unsigned short)b;
  }
  __syncthreads();
  for(int i=t;i<ne;i+=256){
    uint2 r = lbuf[i];
    int b = (int)sbkt[i];
    int rel = gbs[b] + (i - scn[b]);
    if(rel < BCAP){
      ebuf[(size_t)b*BCAP + rel] = r;
    } else {
      int d = (b << BSHIFT) + (int)(r.x >> 17);
      int pos = rowptr[d+1] - 1 - atomicAdd(&fill[d], 1);
      uint2 pr; pr.x = r.x & 0x1FFFFu; pr.y = r.y;
      s_srcw[pos] = pr;
    }
  }
}

__global__ __launch_bounds__(256) void k_place(const int* __restrict__ bcnt, const uint2* __restrict__ ebuf,
                                               const int* __restrict__ rowptr, uint2* __restrict__ s_srcw){
  __shared__ int lrow[128];
  __shared__ int lfill[128];
  int b = blockIdx.x, t = threadIdx.x;
  if(t < 128){
    int n = (b << BSHIFT) + t;
    lrow[t] = (n < N_NODES) ? rowptr[n] : 0;
    lfill[t] = 0;
  }
  __syncthreads();
  int cnt = bcnt[b]; if(cnt > BCAP) cnt = BCAP;
  const uint2* eb = ebuf + (size_t)b*BCAP;
  for(int i=t;i<cnt;i+=256){
    uint2 r = eb[i];
    int dloc = (int)(r.x >> 17);
    int pos = lrow[dloc] + atomicAdd(&lfill[dloc], 1);
    uint2 pr; pr.x = r.x & 0x1FFFFu; pr.y = r.y;
    s_srcw[pos] = pr;
  }
}

// ---------------- GCN ----------------
__global__ __launch_bounds__(256) void k_gcn(const u32* __restrict__ hb, const int* __restrict__ rowptr,
                                             const uint2* __restrict__ s_srcw,
                                             const u64* __restrict__ pk,
                                             const float* __restrict__ gcnb, const float* __restrict__ bnm,
                                             const float* __restrict__ bnv, const float* __restrict__ bnw,
                                             const float* __restrict__ bnb, float* __restrict__ xp1){
  int wave = threadIdx.x >> 6;
  int lane = threadIdx.x & 63;
  int n = blockIdx.x*4 + wave;
  if(n >= N_NODES) return;
  int l = lane & 15, g = lane >> 4;
  bool t0 = (l == 0);
  float dn = rsqrtf(degof(pk[n]) + 1.f);
  const u32* srow = hb + (size_t)n*17;
  u32 us  = srow[l];
  u32 ust = t0 ? srow[16] : 0u;
  float acc0, acc1, acct;
  if(g == 0){ acc0 = dn*bflo(us); acc1 = dn*bfhi(us); acct = dn*bflo(ust); }
  else      { acc0 = 0.f; acc1 = 0.f; acct = 0.f; }
  int rb = rowptr[n], re = rowptr[n+1];
  int j = rb;
  for(; j+8 <= re; j += 8){
    uint2 prA = s_srcw[j + g];
    uint2 prB = s_srcw[j + 4 + g];
    float geA = __uint_as_float(prA.y);
    float geB = __uint_as_float(prB.y);
    const u32* rA = hb + (size_t)prA.x*17;
    const u32* rB = hb + (size_t)prB.x*17;
    u32 uA  = rA[l], uB = rB[l];
    u32 utA = t0 ? rA[16] : 0u;
    u32 utB = t0 ? rB[16] : 0u;
    acc0 = fmaf(geA, bflo(uA),  fmaf(geB, bflo(uB),  acc0));
    acc1 = fmaf(geA, bfhi(uA),  fmaf(geB, bfhi(uB),  acc1));
    acct = fmaf(geA, bflo(utA), fmaf(geB, bflo(utB), acct));
  }
  if(j+4 <= re){
    uint2 pr = s_srcw[j + g];
    float ge = __uint_as_float(pr.y);
    const u32* r = hb + (size_t)pr.x*17;
    u32 u  = r[l];
    u32 ut = t0 ? r[16] : 0u;
    acc0 = fmaf(ge, bflo(u),  acc0);
    acc1 = fmaf(ge, bfhi(u),  acc1);
    acct = fmaf(ge, bflo(ut), acct);
    j += 4;
  }
  int rem = re - j;
  if(rem > 0){
    bool val = (g < rem);
    uint2 pr = s_srcw[val ? (j + g) : j];
    float ge = val ? __uint_as_float(pr.y) : 0.f;
    const u32* r = hb + (size_t)pr.x*17;
    u32 u  = r[l];
    u32 ut = t0 ? r[16] : 0u;
    acc0 = fmaf(ge, bflo(u),  acc0);
    acc1 = fmaf(ge, bfhi(u),  acc1);
    acct = fmaf(ge, bflo(ut), acct);
  }
  #pragma unroll
  for(int m=16;m<=32;m<<=1){
    acc0 += __shfl_xor(acc0, m, 64);
    acc1 += __shfl_xor(acc1, m, 64);
    acct += __shfl_xor(acct, m, 64);
  }
  if(g == 0){
    int c0 = 2*l, c1 = 2*l+1;
    float v0 = fmaxf(dn*acc0 + gcnb[c0], 0.f);
    float v1 = fmaxf(dn*acc1 + gcnb[c1], 0.f);
    float i0 = bnw[c0] / sqrtf(bnv[c0] + BN_EPS);
    float i1 = bnw[c1] / sqrtf(bnv[c1] + BN_EPS);
    float2 o;
    o.x = v0*i0 + (bnb[c0] - bnm[c0]*i0);
    o.y = v1*i1 + (bnb[c1] - bnm[c1]*i1);
    ((float2*)(xp1 + (size_t)n*36))[l] = o;
    if(t0){
      float vt = fmaxf(dn*acct + gcnb[32], 0.f);
      float it = bnw[32] / sqrtf(bnv[32] + BN_EPS);
      float2 ot; ot.x = vt*it + (bnb[32] - bnm[32]*it); ot.y = 0.f;
      ((float2*)(xp1 + (size_t)n*36))[16] = ot;
      float2 z; z.x = 0.f; z.y = 0.f;
      ((float2*)(xp1 + (size_t)n*36))[17] = z;
    }
  }
}

// ---------------- GATv2 ----------------
// xlb row layout (stride 72 u32): per head h at h*36: slots 0..31 = ch 0..63
// (fp16 pairs), slot 32 = ch 64,65 (fp16), slot 33 = fp32 bits of slope/ln2*dotL,
// slots 34,35 pad. dotL = u[h].x[n], u precontracted per block.
__global__ __launch_bounds__(320) void k_gatlin(const float* __restrict__ xp1, const float* __restrict__ wl,
                                                const float* __restrict__ wr, const float* __restrict__ att,
                                                u32* __restrict__ xlb, float* __restrict__ xr){
  __shared__ float sx[64*36];
  __shared__ float swle[66*33];
  __shared__ float swlo[66*33];
  __shared__ float swre[66*33];
  __shared__ float swro[66*33];
  __shared__ float su[2][33];
  int t = threadIdx.x;
  int n0 = blockIdx.x*64;
  int nn = N_NODES - n0; if(nn > 64) nn = 64;
  for(int i=t;i<2178;i+=320){
    int d = i/33, k = i - d*33;
    int gb = d*66 + k;
    swle[i] = wl[gb];
    swlo[i] = wl[gb+33];
    swre[i] = wr[gb];
    swro[i] = wr[gb+33];
  }
  int xcnt = nn*36;
  for(int i=t;i<xcnt;i+=320) sx[i] = xp1[(size_t)n0*36 + i];
  __syncthreads();
  if(t < 66){
    int hh = (t >= 33) ? 1 : 0;
    int k = t - 33*hh;
    float s = 0.f;
    const float* ah = att + hh*66;
    #pragma unroll 3
    for(int dd=0;dd<33;dd++){
      int p = hh*33 + dd;
      s = fmaf(ah[2*dd],   swle[p*33+k], s);
      s = fmaf(ah[2*dd+1], swlo[p*33+k], s);
    }
    su[hh][k] = s;
  }
  if(t < 264){
    int ng = t/66, p = t - ng*66;
    int nbase = ng*16;
    float al0[16], al1[16], ar0[16], ar1[16];
    #pragma unroll
    for(int i=0;i<16;i++){ al0[i]=0.f; al1[i]=0.f; ar0[i]=0.f; ar1[i]=0.f; }
    const float* wle = swle + p*33;
    const float* wlo = swlo + p*33;
    const float* wre = swre + p*33;
    const float* wro = swro + p*33;
    for(int k=0;k<33;k++){
      float w0 = wle[k], w1 = wlo[k], w2 = wre[k], w3 = wro[k];
      const float* xcol = sx + nbase*36 + k;
      #pragma unroll
      for(int i=0;i<16;i++){
        float x = xcol[i*36];
        al0[i] = fmaf(x, w0, al0[i]);
        al1[i] = fmaf(x, w1, al1[i]);
        ar0[i] = fmaf(x, w2, ar0[i]);
        ar1[i] = fmaf(x, w3, ar1[i]);
      }
    }
    int head = (p >= 33) ? 1 : 0;
    int dd = p - 33*head;
    #pragma unroll
    for(int i=0;i<16;i++){
      int n = nbase + i;
      if(n < nn){
        size_t nidx = (size_t)(n0 + n);
        xlb[nidx*72 + head*36 + dd] = packh(al0[i], al1[i]);
        float2 v; v.x = ar0[i]; v.y = ar1[i];
        ((float2*)xr)[nidx*66 + p] = v;
      }
    }
  }
  __syncthreads();
  if(t < 128){
    int nl = t >> 1, hh = t & 1;
    if(nl < nn){
      const float* xv = sx + nl*36;
      float s = 0.f;
      #pragma unroll
      for(int k=0;k<33;k++) s = fmaf(su[hh][k], xv[k], s);
      xlb[(size_t)(n0 + nl)*72 + hh*36 + 33] =
        __float_as_uint(s * (LRELU_SLOPE*1.44269504089f));
    }
  }
}

// 2 nodes/block (256 thr); per node 2 head-waves; wave = 8 x 8-lane groups.
// fp16 packed score; depth-2 pipeline; dotR cancels in softmax (dropped).
__global__ __launch_bounds__(256) void k_gat(const int* __restrict__ rowptr, const u32* __restrict__ srcx,
                                             const u32* __restrict__ xlb, const float* __restrict__ xr,
                                             const float* __restrict__ att, const float* __restrict__ gatb,
                                             float* __restrict__ xp2){
  const float ATT_SC = (1.f - LRELU_SLOPE) * 1.44269504089f;
  int n = blockIdx.x*2 + (threadIdx.x >> 7);
  int h = (threadIdx.x >> 6) & 1;
  int lane = threadIdx.x & 63;
  int l8 = lane & 7, g8 = lane >> 3;
  bool t0 = (l8 == 0);
  bool g0 = (g8 == 0);
  const float* xrp = xr + (size_t)n*132 + h*66 + 8*l8;
  float2 x01 = ((const float2*)xrp)[0];
  float2 x23 = ((const float2*)xrp)[1];
  float2 x45 = ((const float2*)xrp)[2];
  float2 x67 = ((const float2*)xrp)[3];
  float2 xt  = t0 ? *(const float2*)(xr + (size_t)n*132 + h*66 + 64) : make_float2(0.f,0.f);
  u32 xh0 = packh(x01.x, x01.y);
  u32 xh1 = packh(x23.x, x23.y);
  u32 xh2 = packh(x45.x, x45.y);
  u32 xh3 = packh(x67.x, x67.y);
  u32 xht = t0 ? packh(xt.x, xt.y) : 0u;
  const float* ap = att + h*66 + 8*l8;
  float2 a01 = ((const float2*)ap)[0];
  float2 a23 = ((const float2*)ap)[1];
  float2 a45 = ((const float2*)ap)[2];
  float2 a67 = ((const float2*)ap)[3];
  float2 atl = *(const float2*)(att + h*66 + 64);
  u32 ah0 = packh(a01.x*ATT_SC, a01.y*ATT_SC);
  u32 ah1 = packh(a23.x*ATT_SC, a23.y*ATT_SC);
  u32 ah2 = packh(a45.x*ATT_SC, a45.y*ATT_SC);
  u32 ah3 = packh(a67.x*ATT_SC, a67.y*ATT_SC);
  u32 aht = packh(atl.x*ATT_SC, atl.y*ATT_SC);

  const u32* xbase = xlb + h*36;
  float v0,v1,v2,v3,v4,v5,v6,v7,w0,w1;

#define GSCORE(U, TU, P) { \
  u32 q0 = pkmax0(pkadd(U.x, xh0)); \
  u32 q1 = pkmax0(pkadd(U.y, xh1)); \
  u32 q2 = pkmax0(pkadd(U.z, xh2)); \
  u32 q3 = pkmax0(pkadd(U.w, xh3)); \
  u32 qt = pkmax0(pkadd(TU.x, xht)); \
  float pA = __uint_as_float(TU.y); \
  float pB = 0.f; \
  pA = dot2(q0, ah0, pA); \
  pB = dot2(q1, ah1, pB); \
  pA = dot2(q2, ah2, pA); \
  pB = dot2(q3, ah3, pB); \
  pB = dot2(qt, aht, pB); \
  v0 = hlo(U.x); v1 = hhi(U.x); \
  v2 = hlo(U.y); v3 = hhi(U.y); \
  v4 = hlo(U.z); v5 = hhi(U.z); \
  v6 = hlo(U.w); v7 = hhi(U.w); \
  w0 = hlo(TU.x); w1 = hhi(TU.x); \
  P = red8(pA + pB); }

  const u32* srow = xbase + (size_t)n*72;
  uint4 su = ((const uint4*)srow)[l8];
  uint2 stl = t0 ? ((const uint2*)srow)[16] : make_uint2(0u,0u);
  float ps;
  GSCORE(su, stl, ps);
  float cn = -ps;
  float A0 = g0? v0 : 0.f, A1 = g0? v1 : 0.f, A2 = g0? v2 : 0.f, A3 = g0? v3 : 0.f;
  float A4 = g0? v4 : 0.f, A5 = g0? v5 : 0.f, A6 = g0? v6 : 0.f, A7 = g0? v7 : 0.f;
  float T0 = g0? w0 : 0.f, T1 = g0? w1 : 0.f;
  float asum = g0 ? 1.f : 0.f;

  int rb = rowptr[n], re = rowptr[n+1];
  int j = rb;
  int nfull = (re - rb) >> 3;
  uint4 u_n = make_uint4(0u,0u,0u,0u);
  uint2 tu_n = make_uint2(0u,0u);
  if(nfull > 0){
    int s = (int)srcx[2*(j + g8)];
    const u32* r = xbase + (size_t)s*72;
    u_n = ((const uint4*)r)[l8];
    if(t0) tu_n = ((const uint2*)r)[16];
  }
  for(int it=0; it<nfull; ++it){
    uint4 u = u_n; uint2 tu = tu_n;
    if(it+1 < nfull){
      int s2 = (int)srcx[2*(j + 8 + g8)];
      const u32* r2 = xbase + (size_t)s2*72;
      u_n = ((const uint4*)r2)[l8];
      if(t0) tu_n = ((const uint2*)r2)[16];
      else   tu_n = make_uint2(0u,0u);
    }
    float p;
    GSCORE(u, tu, p);
    float a = __builtin_amdgcn_exp2f(p + cn);
    A0 = fmaf(a, v0, A0); A1 = fmaf(a, v1, A1); A2 = fmaf(a, v2, A2); A3 = fmaf(a, v3, A3);
    A4 = fmaf(a, v4, A4); A5 = fmaf(a, v5, A5); A6 = fmaf(a, v6, A6); A7 = fmaf(a, v7, A7);
    T0 = fmaf(a, w0, T0); T1 = fmaf(a, w1, T1);
    asum += a;
    j += 8;
  }
  int rem = re - j;
  if(rem > 0){
    bool val = (g8 < rem);
    int s = val ? (int)srcx[2*(j + g8)] : n;
    const u32* r = xbase + (size_t)s*72;
    uint4 u = ((const uint4*)r)[l8];
    uint2 tu = t0 ? ((const uint2*)r)[16] : make_uint2(0u,0u);
    float p;
    GSCORE(u, tu, p);
    float a = val ? __builtin_amdgcn_exp2f(p + cn) : 0.f;
    A0 = fmaf(a, v0, A0); A1 = fmaf(a, v1, A1); A2 = fmaf(a, v2, A2); A3 = fmaf(a, v3, A3);
    A4 = fmaf(a, v4, A4); A5 = fmaf(a, v5, A5); A6 = fmaf(a, v6, A6); A7 = fmaf(a, v7, A7);
    T0 = fmaf(a, w0, T0); T1 = fmaf(a, w1, T1);
    asum += a;
  }
#undef GSCORE

  A0 = redall(A0); A1 = redall(A1); A2 = redall(A2); A3 = redall(A3);
  A4 = redall(A4); A5 = redall(A5); A6 = redall(A6); A7 = redall(A7);
  T0 = redall(T0); T1 = redall(T1);
  asum = redall(asum);

  if(g0){
    float inv = 1.f / asum;
    const float* gp = gatb + h*66 + 8*l8;
    float2 g01 = ((const float2*)gp)[0];
    float2 g23 = ((const float2*)gp)[1];
    float2 g45 = ((const float2*)gp)[2];
    float2 g67 = ((const float2*)gp)[3];
    float* op = xp2 + (size_t)n*132 + h*66 + 8*l8;
    float2 o;
    o.x = fmaxf(fmaf(A0,inv,g01.x),0.f); o.y = fmaxf(fmaf(A1,inv,g01.y),0.f); ((float2*)op)[0] = o;
    o.x = fmaxf(fmaf(A2,inv,g23.x),0.f); o.y = fmaxf(fmaf(A3,inv,g23.y),0.f); ((float2*)op)[1] = o;
    o.x = fmaxf(fmaf(A4,inv,g45.x),0.f); o.y = fmaxf(fmaf(A5,inv,g45.y),0.f); ((float2*)op)[2] = o;
    o.x = fmaxf(fmaf(A6,inv,g67.x),0.f); o.y = fmaxf(fmaf(A7,inv,g67.y),0.f); ((float2*)op)[3] = o;
    if(t0){
      float2 gt = *(const float2*)(gatb + h*66 + 64);
      float2 ot;
      ot.x = fmaxf(fmaf(T0,inv,gt.x),0.f); ot.y = fmaxf(fmaf(T1,inv,gt.y),0.f);
      *(float2*)(xp2 + (size_t)n*132 + h*66 + 64) = ot;
    }
  }
}

// ---------------- pooling + MLP head ----------------
__global__ __launch_bounds__(256) void k_bounds(const int* __restrict__ batch, int* __restrict__ gstart,
                                                int* __restrict__ gend){
  int n = blockIdx.x*256 + threadIdx.x;
  if(n >= N_NODES) return;
  int b = batch[n];
  if(n == 0) gstart[b] = 0;
  else {
    int p = batch[n-1];
    if(p != b){ gstart[b] = n; gend[p] = n; }
  }
  if(n == N_NODES-1) gend[b] = N_NODES;
}

__global__ __launch_bounds__(128) void k_poolp(const float* __restrict__ xp2, const int* __restrict__ gstart,
                                               const int* __restrict__ gend, float* __restrict__ pp){
  int g = blockIdx.x, seg = blockIdx.y, t = threadIdx.x;
  int s = gstart[g], e = gend[g];
  int len = e - s; if(len < 0) len = 0;
  int ns = s + (int)(((long long)len*seg)>>4);
  int ne = s + (int)(((long long)len*(seg+1))>>4);
  float a0 = 0.f, a1 = 0.f;
  for(int n=ns;n<ne;n++){
    a0 += xp2[(size_t)n*132 + t];
    if(t < 4) a1 += xp2[(size_t)n*132 + 128 + t];
  }
  float* o = pp + (size_t)(g*16 + seg)*132;
  o[t] = a0;
  if(t < 4) o[128 + t] = a1;
}

__global__ __launch_bounds__(256) void k_pfc1(const float* __restrict__ pp, const int* __restrict__ gstart,
                                              const int* __restrict__ gend, const float* __restrict__ w,
                                              const float* __restrict__ b, float* __restrict__ h1T){
  __shared__ float pooled[132];
  int g = blockIdx.x, t = threadIdx.x;
  if(t < 132){
    float s = 0.f;
    #pragma unroll
    for(int k=0;k<16;k++) s += pp[(size_t)(g*16 + k)*132 + t];
    int c = gend[g] - gstart[g]; if(c < 1) c = 1;
    pooled[t] = s/(float)c;
  }
  __syncthreads();
  #pragma unroll
  for(int r=0;r<4;r++){
    int o = r*256 + t;
    const float* wr = w + o*132;
    float acc = b[o];
    for(int k=0;k<132;k++) acc = fmaf(pooled[k], wr[k], acc);
    h1T[o*64+g] = fmaxf(acc, 0.f);
  }
}

__global__ __launch_bounds__(256) void k_fc2(const float* __restrict__ h1T, const float* __restrict__ w,
                                             const float* __restrict__ b, float* __restrict__ out){
  __shared__ float part[256];
  int o = blockIdx.x, t = threadIdx.x;
  int s = t >> 6, g = t & 63;
  const float* wr = w + o*1024 + s*256;
  const float* hp = h1T + (size_t)(s*256)*64 + g;
  float acc = 0.f;
  for(int k=0;k<256;k++) acc = fmaf(hp[k*64], wr[k], acc);
  part[t] = acc;
  __syncthreads();
  if(s == 0){
    float r = b[o] + part[g] + part[64+g] + part[128+g] + part[192+g];
    out[8192 + g*128 + o] = r;
  }
}

// ---------------- RNA branches ----------------
__device__ void sgather_body(const int* __restrict__ sci, const int* __restrict__ off,
                             const float* __restrict__ w, int V, int wstride,
                             int sstride, float* __restrict__ S,
                             int b, int q, int nsplit, int* loff, int* lci, int t){
  if(t <= V) loff[t] = off[b*(V+1) + t];
  __syncthreads();
  int vs = (V*q)/nsplit, ve = (V*(q+1))/nsplit;
  if(vs == ve) return;
  int p0 = loff[vs], p1 = loff[ve];
  for(int i=p0+t;i<p1;i+=256) lci[i-p0] = sci[b*3000 + i];
  __syncthreads();
  int co = t >> 3, kk = t & 7;
  const float* wrow = w + co*wstride + kk;
  float* Srow = S + (size_t)b*32*sstride + co*sstride + kk;
  for(int v=vs;v<ve;v++){
    int j = loff[v] - p0, je = loff[v+1] - p0;
    float a0=0.f,a1=0.f,a2=0.f,a3=0.f,a4=0.f,a5=0.f,a6=0.f,a7=0.f;
    for(; j+8 <= je; j += 8){
      a0 += wrow[lci[j]];
      a1 += wrow[lci[j+1]];
      a2 += wrow[lci[j+2]];
      a3 += wrow[lci[j+3]];
      a4 += wrow[lci[j+4]];
      a5 += wrow[lci[j+5]];
      a6 += wrow[lci[j+6]];
      a7 += wrow[lci[j+7]];
    }
    for(; j<je; j++) a0 += wrow[lci[j]];
    Srow[v*8] = ((a0+a1)+(a2+a3)) + ((a4+a5)+(a6+a7));
  }
}

__global__ __launch_bounds__(256) void k_sgather(const int* __restrict__ sci1, const int* __restrict__ off1,
                                                 const float* __restrict__ w1, float* __restrict__ S1,
                                                 const int* __restrict__ sci2, const int* __restrict__ off2,
                                                 const float* __restrict__ w2, float* __restrict__ S2){
  __shared__ int loff[66];
  __shared__ int lci[3000];
  int b = blockIdx.x, q = blockIdx.y, t = threadIdx.x;
  if(q < 5) sgather_body(sci1, off1, w1, 5, 24000, 40, S1, b, q, 5, loff, lci, t);
  else      sgather_body(sci2, off2, w2, 65, 23984, 520, S2, b, q-5, 32, loff, lci, t);
}

__global__ __launch_bounds__(128) void k_y(const float* __restrict__ S1, const float* __restrict__ S2,
                                           const float* __restrict__ emb1, const float* __restrict__ emb2,
                                           const float* __restrict__ c1b, const float* __restrict__ c2b,
                                           float* __restrict__ ysum){
  __shared__ float em1[640];
  __shared__ float em2[8320];
  __shared__ float Sa[320];
  __shared__ float Sb[4160];
  int b = blockIdx.x, cg = blockIdx.y, t = threadIdx.x;
  for(int i=t;i<640;i+=128)  em1[i] = emb1[i];
  for(int i=t;i<8320;i+=128) em2[i] = emb2[i];
  for(int i=t;i<320;i+=128)  Sa[i] = S1[b*1280 + cg*320 + i];
  for(int i=t;i<4160;i+=128) Sb[i] = S2[(size_t)b*16640 + cg*4160 + i];
  __syncthreads();
  if(t >= 121) return;
  #pragma unroll
  for(int c8=0;c8<8;c8++){
    int co = cg*8 + c8;
    const float* sa = Sa + c8*40;
    float acc1 = c1b[co];
    #pragma unroll
    for(int v=0;v<5;v++)
      #pragma unroll
      for(int k=0;k<8;k++) acc1 = fmaf(sa[v*8+k], em1[v*128 + t + k], acc1);
    const float* sb = Sb + c8*520;
    float acc2 = c2b[co];
    for(int v=0;v<65;v++){
      #pragma unroll
      for(int k=0;k<8;k++) acc2 = fmaf(sb[v*8+k], em2[v*128 + t + k], acc2);
    }
    ysum[b*3872 + co*121 + t] = 0.5f*(acc1 + acc2);
  }
}

__global__ __launch_bounds__(256) void k_fcxr(const float* __restrict__ ysum, const float* __restrict__ fcw,
                                              const float* __restrict__ fcb, float* __restrict__ out){
  __shared__ float part[512];
  int bp = blockIdx.x, q = blockIdx.y, t = threadIdx.x;
  int b0 = bp*2;
  int ol = t >> 3;
  int o  = q*32 + ol;
  int slice = t & 7;
  const float4* ys0 = (const float4*)(ysum + b0*3872) + slice*121;
  const float4* ys1 = (const float4*)(ysum + (b0+1)*3872) + slice*121;
  const float4* wr  = (const float4*)(fcw + (size_t)o*3872) + slice*121;
  float acc0 = 0.f, acc1 = 0.f;
  for(int k=0;k<121;k++){
    float4 w4 = wr[k];
    float4 y0 = ys0[k], y1 = ys1[k];
    acc0 += y0.x*w4.x + y0.y*w4.y + y0.z*w4.z + y0.w*w4.w;
    acc1 += y1.x*w4.x + y1.y*w4.y + y1.z*w4.z + y1.w*w4.w;
  }
  part[t] = acc0;
  part[256+t] = acc1;
  __syncthreads();
  if(slice == 0){
    float s0 = fcb[o], s1 = fcb[o];
    #pragma unroll
    for(int i=0;i<8;i++){ s0 += part[ol*8 + i]; s1 += part[256 + ol*8 + i]; }
    out[b0*128 + o] = s0;
    out[(b0+1)*128 + o] = s1;
  }
}

extern "C" void kernel_launch(void* const* d_in, const int* in_sizes, int n_in,
                              void* d_out, int out_size, void* d_ws, size_t ws_size,
                              hipStream_t stream){
  const int*   g_rna = (const int*)  d_in[0];
  const int*   l_rna = (const int*)  d_in[1];
  const float* pro_x = (const float*)d_in[2];
  const int*   eidx  = (const int*)  d_in[3];
  const float* pro_w = (const float*)d_in[4];
  const int*   batch = (const int*)  d_in[5];
  const float* emb1  = (const float*)d_in[6];
  const float* emb2  = (const float*)d_in[7];
  const float* c1w   = (const float*)d_in[8];
  const float* c1b   = (const float*)d_in[9];
  const float* c2w   = (const float*)d_in[10];
  const float* c2b   = (const float*)d_in[11];
  const float* fcxw  = (const float*)d_in[12];
  const float* fcxb  = (const float*)d_in[13];
  const float* gcnw  = (const float*)d_in[14];
  const float* gcnb  = (const float*)d_in[15];
  const float* bnm   = (const float*)d_in[16];
  const float* bnv   = (const float*)d_in[17];
  const float* bnw   = (const float*)d_in[18];
  const float* bnb   = (const float*)d_in[19];
  const float* gwl   = (const float*)d_in[20];
  const float* gwr   = (const float*)d_in[21];
  const float* gatt  = (const float*)d_in[22];
  const float* gatb  = (const float*)d_in[23];
  const float* f1w   = (const float*)d_in[24];
  const float* f1b   = (const float*)d_in[25];
  const float* f2w   = (const float*)d_in[26];
  const float* f2b_  = (const float*)d_in[27];
  float* out = (float*)d_out;

  char* ws = (char*)d_ws;
  size_t off = 0;
  auto A = [&](size_t n)->char*{ char* p = ws + off; off = (off + n + 255) & ~(size_t)255; return p; };
  u64*   pk     = (u64*)  A((size_t)N_NODES*8);
  int*   fill   = (int*)  A((size_t)N_NODES*4);
  int*   bcnt   = (int*)  A((size_t)NBUCK*4);
  size_t zero_bytes = off;
  int*   rowptr = (int*)  A((size_t)(N_NODES+1)*4);
  int*   bsum   = (int*)  A(196*4);
  int*   bbase  = (int*)  A(196*4);
  uint2* s_srcw = (uint2*)A((size_t)N_EDGES*8);
  u32*   hb     = (u32*)  A((size_t)N_NODES*17*4);
  float* xp1    = (float*)A((size_t)N_NODES*36*4);
  u32*   xlb    = (u32*)  A((size_t)N_NODES*72*4);
  float* xr     = (float*)A((size_t)N_NODES*132*4);
  float* xp2    = (float*)A((size_t)N_NODES*132*4);
  int*   gstart = (int*)  A(64*4);
  int*   gend   = (int*)  A(64*4);
  float* pp     = (float*)A((size_t)64*16*132*4);
  float* h1T    = (float*)A(1024*64*4);
  float* S1     = (float*)A((size_t)64*1280*4);
  float* S2     = (float*)A((size_t)64*16640*4);
  float* ysum   = (float*)A((size_t)64*3872*4);
  int*   sci1   = (int*)  A((size_t)64*3000*4);
  int*   off1   = (int*)  A((size_t)64*8*4);
  int*   sci2   = (int*)  A((size_t)64*3000*4);
  int*   off2   = (int*)  A((size_t)64*66*4);
  (void)ws_size; (void)in_sizes; (void)n_in; (void)out_size;

  // ebuf (12.8 MB, uint2 records) aliases xr (26.4 MB): dead until k_gatlin,
  // and the CSR build completes (stream-ordered) before k_gatlin writes xr.
  uint2* ebuf = (uint2*)xr;

  hipMemsetAsync(ws, 0, zero_bytes, stream);

  // fused input-only work: edge histogram + GCN linear + RNA buckets
  k_pre    <<<3449, 256, 0, stream>>>(eidx, pro_w, pk, pro_x, gcnw, hb,
                                      g_rna, l_rna, sci1, off1, sci2, off2);
  // protein CSR build
  k_scan1  <<<196, 256, 0, stream>>>(pk, rowptr, bsum);
  k_scan2  <<<1, 256, 0, stream>>>(bsum, bbase, rowptr, gstart, gend);
  k_scan3  <<<196, 256, 0, stream>>>(rowptr, bbase);
  k_bin    <<<NBLKBIN, 256, 0, stream>>>(eidx, pro_w, pk, rowptr, fill, bcnt, ebuf, s_srcw);
  k_place  <<<NBUCK, 256, 0, stream>>>(bcnt, ebuf, rowptr, s_srcw);
  // protein GNN
  k_gcn    <<<12500, 256, 0, stream>>>(hb, rowptr, s_srcw, pk, gcnb, bnm, bnv, bnw, bnb, xp1);
  k_gatlin <<<782, 320, 0, stream>>>(xp1, gwl, gwr, gatt, xlb, xr);
  k_gat    <<<25000, 256, 0, stream>>>(rowptr, (const u32*)s_srcw, xlb, xr, gatt, gatb, xp2);
  k_bounds <<<196, 256, 0, stream>>>(batch, gstart, gend);
  k_poolp  <<<dim3(64,16), 128, 0, stream>>>(xp2, gstart, gend, pp);
  k_pfc1   <<<64, 256, 0, stream>>>(pp, gstart, gend, f1w, f1b, h1T);
  k_fc2    <<<128, 256, 0, stream>>>(h1T, f2w, f2b_, out);

  // RNA branches
  k_sgather<<<dim3(64,37), 256, 0, stream>>>(sci1, off1, c1w, S1, sci2, off2, c2w, S2);
  k_y      <<<dim3(64,4), 128, 0, stream>>>(S1, S2, emb1, emb2, c1b, c2b, ysum);
  k_fcxr   <<<dim3(32,4), 256, 0, stream>>>(ysum, fcxw, fcxb, out);
}

// Round 9
// 522.181 us; speedup vs baseline: 1.0490x; 1.0042x over previous
//
#include <hip/hip_runtime.h>

#define N_NODES 50000
#define N_EDGES 800000
#define LRELU_SLOPE 0.2f
#define BN_EPS 1e-5f

#define BSHIFT 7
#define NBUCK 391            // ceil(50000/128)
#define BCAP 4096            // mean 2048/bucket; overflow falls back (correct for any dist)
#define EPB 4096             // edges per k_bin block
#define NBLKBIN ((N_EDGES + EPB - 1)/EPB)

typedef unsigned int u32;
typedef unsigned long long u64;

__device__ __forceinline__ float lrelu(float x){ return fmaxf(x,0.f) + LRELU_SLOPE*fminf(x,0.f); }
__device__ __forceinline__ float bflo(u32 u){ return __uint_as_float(u<<16); }
__device__ __forceinline__ float bfhi(u32 u){ return __uint_as_float(u & 0xffff0000u); }
__device__ __forceinline__ u32 packbf(float a, float b){
  u32 ua = __float_as_uint(a); ua = (ua + 0x7fffu + ((ua>>16)&1u)) >> 16;
  u32 ub = __float_as_uint(b); ub = (ub + 0x7fffu + ((ub>>16)&1u)) >> 16;
  return ua | (ub<<16);
}

// fp16 pair in a u32 -- no hip_fp16.h API (header lacks __hmax2 on this ROCm).
typedef _Float16 h2v __attribute__((ext_vector_type(2)));
union uhcv { u32 i; h2v h; };
__device__ __forceinline__ u32 packh(float a, float b){
  uhcv c; c.h.x = (_Float16)a; c.h.y = (_Float16)b; return c.i;
}
__device__ __forceinline__ float hlo(u32 u){ uhcv c; c.i = u; return (float)c.h.x; }
__device__ __forceinline__ float hhi(u32 u){ uhcv c; c.i = u; return (float)c.h.y; }
__device__ __forceinline__ h2v toh2(u32 u){ uhcv c; c.i = u; return c.h; }
// packed fp16 ops via asm (VOP3P, baseline gfx9+)
__device__ __forceinline__ u32 pkadd(u32 a, u32 b){
  u32 r; asm("v_pk_add_f16 %0, %1, %2" : "=v"(r) : "v"(a), "v"(b)); return r;
}
__device__ __forceinline__ u32 pkmax0(u32 a){
  u32 r; asm("v_pk_max_f16 %0, %1, %2" : "=v"(r) : "v"(a), "v"(0u)); return r;
}
__device__ __forceinline__ float dot2(u32 a, u32 b, float c){
#if defined(__has_builtin) && __has_builtin(__builtin_amdgcn_fdot2)
  return __builtin_amdgcn_fdot2(toh2(a), toh2(b), c, false);
#else
  float r; asm("v_dot2_f32_f16 %0, %1, %2, %3" : "=v"(r) : "v"(a), "v"(b), "v"(c)); return r;
#endif
}

// packed (cnt<<40 | deg in 2^-26 fixed point)
__device__ __forceinline__ float degof(u64 p){
  return (float)(p & 0xFFFFFFFFFFull) * (1.0f/67108864.0f);
}

// DPP-fused adds: VALU-only lane reduction (no ds_swizzle).
template<int CTRL>
__device__ __forceinline__ float dppadd(float x){
  int y = __builtin_amdgcn_update_dpp(0, __float_as_int(x), CTRL, 0xF, 0xF, false);
  return x + __int_as_float(y);
}
// sum over 8-lane group (lanes differing in bits 0..2)
__device__ __forceinline__ float red8(float p){
  p = dppadd<0x141>(p);  // row_half_mirror: reverse within 8
  p = dppadd<0x4E>(p);   // quad_perm [2,3,0,1] = xor2
  p = dppadd<0xB1>(p);   // quad_perm [1,0,3,2] = xor1
  return p;
}
// sum across the 8 groups (lane bits 3,4,5), keeping l8 lanes separate
__device__ __forceinline__ float redall(float v){
  v = dppadd<0x128>(v);          // row_ror:8 == xor8 within 16-lane row
  v += __shfl_xor(v, 16, 64);
  v += __shfl_xor(v, 32, 64);
  return v;
}

// ---------------- fused input-only kernel: hist + h + buckets + bounds ----------------
__device__ void bucket_body(const int* __restrict__ g, int L, int V,
                            int* __restrict__ sci, int* __restrict__ off,
                            int* shm, int b, int t){
  int* gl   = shm;        // [3000]
  int* hist = shm + 3000; // [65]
  int* base = shm + 3065; // [66]
  if(t < V) hist[t] = 0;
  for(int i=t;i<L;i+=256) gl[i] = g[b*L + i];
  __syncthreads();
  for(int i=t;i<L;i+=256) atomicAdd(&hist[gl[i]], 1);
  __syncthreads();
  if(t == 0){
    int run = 0;
    for(int v=0;v<V;v++){ base[v] = run; run += hist[v]; }
    base[V] = run;
  }
  __syncthreads();
  if(t <= V) off[b*(V+1) + t] = base[t];
  if(t < V) hist[t] = 0;
  __syncthreads();
  for(int i=t;i<L;i+=256){
    int v = gl[i];
    int p = base[v] + atomicAdd(&hist[v], 1);
    sci[b*3000 + p] = i*8;
  }
}

__global__ __launch_bounds__(256) void k_pre(const int* __restrict__ eidx, const float* __restrict__ pw,
                                             u64* __restrict__ pk,
                                             const float* __restrict__ px, const float* __restrict__ gw,
                                             u32* __restrict__ hb,
                                             const int* __restrict__ grna, const int* __restrict__ lrna,
                                             int* __restrict__ sci1, int* __restrict__ off1,
                                             int* __restrict__ sci2, int* __restrict__ off2,
                                             const int* __restrict__ batch, int* __restrict__ gstart,
                                             int* __restrict__ gend){
  __shared__ int shm[3131];
  int b = blockIdx.x, t = threadIdx.x;
  if(b < 3125){
    // k_hist region (3125*256 == N_EDGES exactly)
    int e = b*256 + t;
    int d = eidx[N_EDGES + e];
    u64 q = (u64)(pw[e] * 67108864.f);
    atomicAdd(&pk[d], (1ull<<40) | q);
    return;
  }
  b -= 3125;
  if(b < 196){
    // k_h region
    int n = b*256 + t;
    if(n >= N_NODES) return;
    float x[33];
    #pragma unroll
    for(int k=0;k<33;k++) x[k] = px[n*33+k];
    float a[33];
    for(int c=0;c<33;c++){
      float s = 0.f;
      #pragma unroll
      for(int k=0;k<33;k++) s = fmaf(x[k], gw[c*33+k], s);
      a[c] = s;
    }
    #pragma unroll
    for(int d=0;d<16;d++) hb[(size_t)n*17 + d] = packbf(a[2*d], a[2*d+1]);
    hb[(size_t)n*17 + 16] = packbf(a[32], 0.f);
    return;
  }
  b -= 196;
  if(b < 196){
    // k_bounds region (gstart/gend zero-initialized by the memset; empty
    // graphs keep 0/0 -> len 0 downstream)
    int n = b*256 + t;
    if(n >= N_NODES) return;
    int bb = batch[n];
    if(n == 0) gstart[bb] = 0;
    else {
      int p = batch[n-1];
      if(p != bb){ gstart[bb] = n; gend[p] = n; }
    }
    if(n == N_NODES-1) gend[bb] = N_NODES;
    return;
  }
  b -= 196;
  if(b < 64){ bucket_body(grna, 3000, 5, sci1, off1, shm, b, t); return; }
  b -= 64;
  bucket_body(lrna, 2998, 65, sci2, off2, shm, b, t);
}

// ---------------- CSR build ----------------
__global__ __launch_bounds__(256) void k_scan1(const u64* __restrict__ pk, int* __restrict__ rowptr,
                                               int* __restrict__ bsum){
  __shared__ int sc[256];
  int b = blockIdx.x, t = threadIdx.x;
  int i = b*256 + t;
  int v = (i < N_NODES) ? (int)(pk[i] >> 40) : 0;
  sc[t] = v;
  __syncthreads();
  for(int off=1; off<256; off<<=1){
    int x = (t>=off)? sc[t-off] : 0;
    __syncthreads();
    sc[t] += x;
    __syncthreads();
  }
  if(i < N_NODES) rowptr[i] = sc[t] - v;
  if(t == 255) bsum[b] = sc[255];
}

__global__ __launch_bounds__(256) void k_scan2(const int* __restrict__ bsum, int* __restrict__ bbase,
                                               int* __restrict__ rowptr){
  __shared__ int sc[256];
  int t = threadIdx.x;
  int v = (t < 196) ? bsum[t] : 0;
  sc[t] = v;
  __syncthreads();
  for(int off=1; off<256; off<<=1){
    int x = (t>=off)? sc[t-off] : 0;
    __syncthreads();
    sc[t] += x;
    __syncthreads();
  }
  if(t < 196) bbase[t] = sc[t] - v;
  if(t == 255) rowptr[N_NODES] = sc[255];
}

__global__ __launch_bounds__(256) void k_scan3(int* __restrict__ rowptr, const int* __restrict__ bbase){
  int b = blockIdx.x, t = threadIdx.x;
  int i = b*256 + t;
  if(i < N_NODES) rowptr[i] += bbase[b];
}

// Block-aggregated binning: per-edge work stays in LDS; global atomics only
// per (block,bucket). Output ebuf written coalesced in bucket-sorted runs.
__global__ __launch_bounds__(256) void k_bin(const int* __restrict__ eidx, const float* __restrict__ pw,
                                             const u64* __restrict__ pk, const int* __restrict__ rowptr,
                                             int* __restrict__ fill, int* __restrict__ bcnt,
                                             uint2* __restrict__ ebuf, uint2* __restrict__ s_srcw){
  __shared__ int hist[NBUCK];
  __shared__ int scn[NBUCK];
  __shared__ int gbs[NBUCK];
  __shared__ uint2 lbuf[EPB];
  __shared__ unsigned short sbkt[EPB];
  int t = threadIdx.x;
  int e0 = blockIdx.x*EPB;
  int ne = N_EDGES - e0; if(ne > EPB) ne = EPB;
  for(int i=t;i<NBUCK;i+=256) hist[i] = 0;
  __syncthreads();
  for(int i=t;i<ne;i+=256) atomicAdd(&hist[eidx[N_EDGES + e0 + i] >> BSHIFT], 1);
  __syncthreads();
  for(int i=t;i<NBUCK;i+=256) scn[i] = hist[i];
  __syncthreads();
  for(int off=1; off<NBUCK; off<<=1){
    int i0 = t, i1 = t + 256;
    int v0 = (i0 < NBUCK && i0 >= off) ? scn[i0-off] : 0;
    int v1 = (i1 < NBUCK && i1 >= off) ? scn[i1-off] : 0;
    __syncthreads();
    if(i0 < NBUCK) scn[i0] += v0;
    if(i1 < NBUCK) scn[i1] += v1;
    __syncthreads();
  }
  for(int i=t;i<NBUCK;i+=256){
    int c = hist[i];
    gbs[i] = c ? atomicAdd(&bcnt[i], c) : 0;
    scn[i] -= c;
    hist[i] = 0;
  }
  __syncthreads();
  for(int i=t;i<ne;i+=256){
    int e = e0 + i;
    int d = eidx[N_EDGES + e];
    int s = eidx[e];
    float ge = rsqrtf(degof(pk[s]) + 1.f) * pw[e];
    int b = d >> BSHIFT;
    int slot = scn[b] + atomicAdd(&hist[b], 1);
    uint2 r; r.x = (u32)s | ((u32)(d & ((1<<BSHIFT)-1)) << 17); r.y = __float_as_uint(ge);
    lbuf[slot] = r;
    sbkt[slot] = (unsigned short)b;
  }
  __syncthreads();
  for(int i=t;i<ne;i+=256){
    uint2 r = lbuf[i];
    int b = (int)sbkt[i];
    int rel = gbs[b] + (i - scn[b]);
    if(rel < BCAP){
      ebuf[(size_t)b*BCAP + rel] = r;
    } else {
      int d = (b << BSHIFT) + (int)(r.x >> 17);
      int pos = rowptr[d+1] - 1 - atomicAdd(&fill[d], 1);
      uint2 pr; pr.x = r.x & 0x1FFFFu; pr.y = r.y;
      s_srcw[pos] = pr;
    }
  }
}

__global__ __launch_bounds__(256) void k_place(const int* __restrict__ bcnt, const uint2* __restrict__ ebuf,
                                               const int* __restrict__ rowptr, uint2* __restrict__ s_srcw){
  __shared__ int lrow[128];
  __shared__ int lfill[128];
  int b = blockIdx.x, t = threadIdx.x;
  if(t < 128){
    int n = (b << BSHIFT) + t;
    lrow[t] = (n < N_NODES) ? rowptr[n] : 0;
    lfill[t] = 0;
  }
  __syncthreads();
  int cnt = bcnt[b]; if(cnt > BCAP) cnt = BCAP;
  const uint2* eb = ebuf + (size_t)b*BCAP;
  for(int i=t;i<cnt;i+=256){
    uint2 r = eb[i];
    int dloc = (int)(r.x >> 17);
    int pos = lrow[dloc] + atomicAdd(&lfill[dloc], 1);
    uint2 pr; pr.x = r.x & 0x1FFFFu; pr.y = r.y;
    s_srcw[pos] = pr;
  }
}

// ---------------- GCN ----------------
__global__ __launch_bounds__(256) void k_gcn(const u32* __restrict__ hb, const int* __restrict__ rowptr,
                                             const uint2* __restrict__ s_srcw,
                                             const u64* __restrict__ pk,
                                             const float* __restrict__ gcnb, const float* __restrict__ bnm,
                                             const float* __restrict__ bnv, const float* __restrict__ bnw,
                                             const float* __restrict__ bnb, float* __restrict__ xp1){
  int wave = threadIdx.x >> 6;
  int lane = threadIdx.x & 63;
  int n = blockIdx.x*4 + wave;
  if(n >= N_NODES) return;
  int l = lane & 15, g = lane >> 4;
  bool t0 = (l == 0);
  float dn = rsqrtf(degof(pk[n]) + 1.f);
  const u32* srow = hb + (size_t)n*17;
  u32 us  = srow[l];
  u32 ust = t0 ? srow[16] : 0u;
  float acc0, acc1, acct;
  if(g == 0){ acc0 = dn*bflo(us); acc1 = dn*bfhi(us); acct = dn*bflo(ust); }
  else      { acc0 = 0.f; acc1 = 0.f; acct = 0.f; }
  int rb = rowptr[n], re = rowptr[n+1];
  int j = rb;
  for(; j+8 <= re; j += 8){
    uint2 prA = s_srcw[j + g];
    uint2 prB = s_srcw[j + 4 + g];
    float geA = __uint_as_float(prA.y);
    float geB = __uint_as_float(prB.y);
    const u32* rA = hb + (size_t)prA.x*17;
    const u32* rB = hb + (size_t)prB.x*17;
    u32 uA  = rA[l], uB = rB[l];
    u32 utA = t0 ? rA[16] : 0u;
    u32 utB = t0 ? rB[16] : 0u;
    acc0 = fmaf(geA, bflo(uA),  fmaf(geB, bflo(uB),  acc0));
    acc1 = fmaf(geA, bfhi(uA),  fmaf(geB, bfhi(uB),  acc1));
    acct = fmaf(geA, bflo(utA), fmaf(geB, bflo(utB), acct));
  }
  if(j+4 <= re){
    uint2 pr = s_srcw[j + g];
    float ge = __uint_as_float(pr.y);
    const u32* r = hb + (size_t)pr.x*17;
    u32 u  = r[l];
    u32 ut = t0 ? r[16] : 0u;
    acc0 = fmaf(ge, bflo(u),  acc0);
    acc1 = fmaf(ge, bfhi(u),  acc1);
    acct = fmaf(ge, bflo(ut), acct);
    j += 4;
  }
  int rem = re - j;
  if(rem > 0){
    bool val = (g < rem);
    uint2 pr = s_srcw[val ? (j + g) : j];
    float ge = val ? __uint_as_float(pr.y) : 0.f;
    const u32* r = hb + (size_t)pr.x*17;
    u32 u  = r[l];
    u32 ut = t0 ? r[16] : 0u;
    acc0 = fmaf(ge, bflo(u),  acc0);
    acc1 = fmaf(ge, bfhi(u),  acc1);
    acct = fmaf(ge, bflo(ut), acct);
  }
  #pragma unroll
  for(int m=16;m<=32;m<<=1){
    acc0 += __shfl_xor(acc0, m, 64);
    acc1 += __shfl_xor(acc1, m, 64);
    acct += __shfl_xor(acct, m, 64);
  }
  if(g == 0){
    int c0 = 2*l, c1 = 2*l+1;
    float v0 = fmaxf(dn*acc0 + gcnb[c0], 0.f);
    float v1 = fmaxf(dn*acc1 + gcnb[c1], 0.f);
    float i0 = bnw[c0] / sqrtf(bnv[c0] + BN_EPS);
    float i1 = bnw[c1] / sqrtf(bnv[c1] + BN_EPS);
    float2 o;
    o.x = v0*i0 + (bnb[c0] - bnm[c0]*i0);
    o.y = v1*i1 + (bnb[c1] - bnm[c1]*i1);
    ((float2*)(xp1 + (size_t)n*36))[l] = o;
    if(t0){
      float vt = fmaxf(dn*acct + gcnb[32], 0.f);
      float it = bnw[32] / sqrtf(bnv[32] + BN_EPS);
      float2 ot; ot.x = vt*it + (bnb[32] - bnm[32]*it); ot.y = 0.f;
      ((float2*)(xp1 + (size_t)n*36))[16] = ot;
      float2 z; z.x = 0.f; z.y = 0.f;
      ((float2*)(xp1 + (size_t)n*36))[17] = z;
    }
  }
}

// ---------------- GATv2 ----------------
// xlb row layout (stride 72 u32): per head h at h*36: slots 0..31 = ch 0..63
// (fp16 pairs), slot 32 = ch 64,65 (fp16), slot 33 = fp32 bits of slope/ln2*dotL,
// slots 34,35 pad. dotL = u[h].x[n], u precontracted per block.
__global__ __launch_bounds__(320) void k_gatlin(const float* __restrict__ xp1, const float* __restrict__ wl,
                                                const float* __restrict__ wr, const float* __restrict__ att,
                                                u32* __restrict__ xlb, float* __restrict__ xr){
  __shared__ float sx[64*36];
  __shared__ float swle[66*33];
  __shared__ float swlo[66*33];
  __shared__ float swre[66*33];
  __shared__ float swro[66*33];
  __shared__ float su[2][33];
  int t = threadIdx.x;
  int n0 = blockIdx.x*64;
  int nn = N_NODES - n0; if(nn > 64) nn = 64;
  for(int i=t;i<2178;i+=320){
    int d = i/33, k = i - d*33;
    int gb = d*66 + k;
    swle[i] = wl[gb];
    swlo[i] = wl[gb+33];
    swre[i] = wr[gb];
    swro[i] = wr[gb+33];
  }
  int xcnt = nn*36;
  for(int i=t;i<xcnt;i+=320) sx[i] = xp1[(size_t)n0*36 + i];
  __syncthreads();
  if(t < 66){
    int hh = (t >= 33) ? 1 : 0;
    int k = t - 33*hh;
    float s = 0.f;
    const float* ah = att + hh*66;
    #pragma unroll 3
    for(int dd=0;dd<33;dd++){
      int p = hh*33 + dd;
      s = fmaf(ah[2*dd],   swle[p*33+k], s);
      s = fmaf(ah[2*dd+1], swlo[p*33+k], s);
    }
    su[hh][k] = s;
  }
  if(t < 264){
    int ng = t/66, p = t - ng*66;
    int nbase = ng*16;
    float al0[16], al1[16], ar0[16], ar1[16];
    #pragma unroll
    for(int i=0;i<16;i++){ al0[i]=0.f; al1[i]=0.f; ar0[i]=0.f; ar1[i]=0.f; }
    const float* wle = swle + p*33;
    const float* wlo = swlo + p*33;
    const float* wre = swre + p*33;
    const float* wro = swro + p*33;
    for(int k=0;k<33;k++){
      float w0 = wle[k], w1 = wlo[k], w2 = wre[k], w3 = wro[k];
      const float* xcol = sx + nbase*36 + k;
      #pragma unroll
      for(int i=0;i<16;i++){
        float x = xcol[i*36];
        al0[i] = fmaf(x, w0, al0[i]);
        al1[i] = fmaf(x, w1, al1[i]);
        ar0[i] = fmaf(x, w2, ar0[i]);
        ar1[i] = fmaf(x, w3, ar1[i]);
      }
    }
    int head = (p >= 33) ? 1 : 0;
    int dd = p - 33*head;
    #pragma unroll
    for(int i=0;i<16;i++){
      int n = nbase + i;
      if(n < nn){
        size_t nidx = (size_t)(n0 + n);
        xlb[nidx*72 + head*36 + dd] = packh(al0[i], al1[i]);
        float2 v; v.x = ar0[i]; v.y = ar1[i];
        ((float2*)xr)[nidx*66 + p] = v;
      }
    }
  }
  __syncthreads();
  if(t < 128){
    int nl = t >> 1, hh = t & 1;
    if(nl < nn){
      const float* xv = sx + nl*36;
      float s = 0.f;
      #pragma unroll
      for(int k=0;k<33;k++) s = fmaf(su[hh][k], xv[k], s);
      xlb[(size_t)(n0 + nl)*72 + hh*36 + 33] =
        __float_as_uint(s * (LRELU_SLOPE*1.44269504089f));
    }
  }
}

// One block/node, 2 head-waves; wave = 8 x 8-lane groups; 8 edges in flight.
// fp16 packed score; depth-2 pipeline; dotR cancels in softmax (dropped).
__global__ __launch_bounds__(128) void k_gat(const int* __restrict__ rowptr, const u32* __restrict__ srcx,
                                             const u32* __restrict__ xlb, const float* __restrict__ xr,
                                             const float* __restrict__ att, const float* __restrict__ gatb,
                                             float* __restrict__ xp2){
  const float ATT_SC = (1.f - LRELU_SLOPE) * 1.44269504089f;
  int n = blockIdx.x;
  int h = threadIdx.x >> 6;
  int lane = threadIdx.x & 63;
  int l8 = lane & 7, g8 = lane >> 3;
  bool t0 = (l8 == 0);
  bool g0 = (g8 == 0);
  const float* xrp = xr + (size_t)n*132 + h*66 + 8*l8;
  float2 x01 = ((const float2*)xrp)[0];
  float2 x23 = ((const float2*)xrp)[1];
  float2 x45 = ((const float2*)xrp)[2];
  float2 x67 = ((const float2*)xrp)[3];
  float2 xt  = t0 ? *(const float2*)(xr + (size_t)n*132 + h*66 + 64) : make_float2(0.f,0.f);
  u32 xh0 = packh(x01.x, x01.y);
  u32 xh1 = packh(x23.x, x23.y);
  u32 xh2 = packh(x45.x, x45.y);
  u32 xh3 = packh(x67.x, x67.y);
  u32 xht = t0 ? packh(xt.x, xt.y) : 0u;
  const float* ap = att + h*66 + 8*l8;
  float2 a01 = ((const float2*)ap)[0];
  float2 a23 = ((const float2*)ap)[1];
  float2 a45 = ((const float2*)ap)[2];
  float2 a67 = ((const float2*)ap)[3];
  float2 atl = *(const float2*)(att + h*66 + 64);
  u32 ah0 = packh(a01.x*ATT_SC, a01.y*ATT_SC);
  u32 ah1 = packh(a23.x*ATT_SC, a23.y*ATT_SC);
  u32 ah2 = packh(a45.x*ATT_SC, a45.y*ATT_SC);
  u32 ah3 = packh(a67.x*ATT_SC, a67.y*ATT_SC);
  u32 aht = packh(atl.x*ATT_SC, atl.y*ATT_SC);

  const u32* xbase = xlb + h*36;
  float v0,v1,v2,v3,v4,v5,v6,v7,w0,w1;

#define GSCORE(U, TU, P) { \
  u32 q0 = pkmax0(pkadd(U.x, xh0)); \
  u32 q1 = pkmax0(pkadd(U.y, xh1)); \
  u32 q2 = pkmax0(pkadd(U.z, xh2)); \
  u32 q3 = pkmax0(pkadd(U.w, xh3)); \
  u32 qt = pkmax0(pkadd(TU.x, xht)); \
  float pA = __uint_as_float(TU.y); \
  float pB = 0.f; \
  pA = dot2(q0, ah0, pA); \
  pB = dot2(q1, ah1, pB); \
  pA = dot2(q2, ah2, pA); \
  pB = dot2(q3, ah3, pB); \
  pB = dot2(qt, aht, pB); \
  v0 = hlo(U.x); v1 = hhi(U.x); \
  v2 = hlo(U.y); v3 = hhi(U.y); \
  v4 = hlo(U.z); v5 = hhi(U.z); \
  v6 = hlo(U.w); v7 = hhi(U.w); \
  w0 = hlo(TU.x); w1 = hhi(TU.x); \
  P = red8(pA + pB); }

  const u32* srow = xbase + (size_t)n*72;
  uint4 su = ((const uint4*)srow)[l8];
  uint2 stl = t0 ? ((const uint2*)srow)[16] : make_uint2(0u,0u);
  float ps;
  GSCORE(su, stl, ps);
  float cn = -ps;
  float A0 = g0? v0 : 0.f, A1 = g0? v1 : 0.f, A2 = g0? v2 : 0.f, A3 = g0? v3 : 0.f;
  float A4 = g0? v4 : 0.f, A5 = g0? v5 : 0.f, A6 = g0? v6 : 0.f, A7 = g0? v7 : 0.f;
  float T0 = g0? w0 : 0.f, T1 = g0? w1 : 0.f;
  float asum = g0 ? 1.f : 0.f;

  int rb = rowptr[n], re = rowptr[n+1];
  int j = rb;
  int nfull = (re - rb) >> 3;
  uint4 u_n = make_uint4(0u,0u,0u,0u);
  uint2 tu_n = make_uint2(0u,0u);
  if(nfull > 0){
    int s = (int)srcx[2*(j + g8)];
    const u32* r = xbase + (size_t)s*72;
    u_n = ((const uint4*)r)[l8];
    if(t0) tu_n = ((const uint2*)r)[16];
  }
  for(int it=0; it<nfull; ++it){
    uint4 u = u_n; uint2 tu = tu_n;
    if(it+1 < nfull){
      int s2 = (int)srcx[2*(j + 8 + g8)];
      const u32* r2 = xbase + (size_t)s2*72;
      u_n = ((const uint4*)r2)[l8];
      if(t0) tu_n = ((const uint2*)r2)[16];
      else   tu_n = make_uint2(0u,0u);
    }
    float p;
    GSCORE(u, tu, p);
    float a = __builtin_amdgcn_exp2f(p + cn);
    A0 = fmaf(a, v0, A0); A1 = fmaf(a, v1, A1); A2 = fmaf(a, v2, A2); A3 = fmaf(a, v3, A3);
    A4 = fmaf(a, v4, A4); A5 = fmaf(a, v5, A5); A6 = fmaf(a, v6, A6); A7 = fmaf(a, v7, A7);
    T0 = fmaf(a, w0, T0); T1 = fmaf(a, w1, T1);
    asum += a;
    j += 8;
  }
  int rem = re - j;
  if(rem > 0){
    bool val = (g8 < rem);
    int s = val ? (int)srcx[2*(j + g8)] : n;
    const u32* r = xbase + (size_t)s*72;
    uint4 u = ((const uint4*)r)[l8];
    uint2 tu = t0 ? ((const uint2*)r)[16] : make_uint2(0u,0u);
    float p;
    GSCORE(u, tu, p);
    float a = val ? __builtin_amdgcn_exp2f(p + cn) : 0.f;
    A0 = fmaf(a, v0, A0); A1 = fmaf(a, v1, A1); A2 = fmaf(a, v2, A2); A3 = fmaf(a, v3, A3);
    A4 = fmaf(a, v4, A4); A5 = fmaf(a, v5, A5); A6 = fmaf(a, v6, A6); A7 = fmaf(a, v7, A7);
    T0 = fmaf(a, w0, T0); T1 = fmaf(a, w1, T1);
    asum += a;
  }
#undef GSCORE

  A0 = redall(A0); A1 = redall(A1); A2 = redall(A2); A3 = redall(A3);
  A4 = redall(A4); A5 = redall(A5); A6 = redall(A6); A7 = redall(A7);
  T0 = redall(T0); T1 = redall(T1);
  asum = redall(asum);

  if(g0){
    float inv = 1.f / asum;
    const float* gp = gatb + h*66 + 8*l8;
    float2 g01 = ((const float2*)gp)[0];
    float2 g23 = ((const float2*)gp)[1];
    float2 g45 = ((const float2*)gp)[2];
    float2 g67 = ((const float2*)gp)[3];
    float* op = xp2 + (size_t)n*132 + h*66 + 8*l8;
    float2 o;
    o.x = fmaxf(fmaf(A0,inv,g01.x),0.f); o.y = fmaxf(fmaf(A1,inv,g01.y),0.f); ((float2*)op)[0] = o;
    o.x = fmaxf(fmaf(A2,inv,g23.x),0.f); o.y = fmaxf(fmaf(A3,inv,g23.y),0.f); ((float2*)op)[1] = o;
    o.x = fmaxf(fmaf(A4,inv,g45.x),0.f); o.y = fmaxf(fmaf(A5,inv,g45.y),0.f); ((float2*)op)[2] = o;
    o.x = fmaxf(fmaf(A6,inv,g67.x),0.f); o.y = fmaxf(fmaf(A7,inv,g67.y),0.f); ((float2*)op)[3] = o;
    if(t0){
      float2 gt = *(const float2*)(gatb + h*66 + 64);
      float2 ot;
      ot.x = fmaxf(fmaf(T0,inv,gt.x),0.f); ot.y = fmaxf(fmaf(T1,inv,gt.y),0.f);
      *(float2*)(xp2 + (size_t)n*132 + h*66 + 64) = ot;
    }
  }
}

// ---------------- pooling + MLP head ----------------
__global__ __launch_bounds__(128) void k_poolp(const float* __restrict__ xp2, const int* __restrict__ gstart,
                                               const int* __restrict__ gend, float* __restrict__ pp){
  int g = blockIdx.x, seg = blockIdx.y, t = threadIdx.x;
  int s = gstart[g], e = gend[g];
  int len = e - s; if(len < 0) len = 0;
  int ns = s + (int)(((long long)len*seg)>>4);
  int ne = s + (int)(((long long)len*(seg+1))>>4);
  float a0 = 0.f, a1 = 0.f;
  for(int n=ns;n<ne;n++){
    a0 += xp2[(size_t)n*132 + t];
    if(t < 4) a1 += xp2[(size_t)n*132 + 128 + t];
  }
  float* o = pp + (size_t)(g*16 + seg)*132;
  o[t] = a0;
  if(t < 4) o[128 + t] = a1;
}

__global__ __launch_bounds__(256) void k_pfc1(const float* __restrict__ pp, const int* __restrict__ gstart,
                                              const int* __restrict__ gend, const float* __restrict__ w,
                                              const float* __restrict__ b, float* __restrict__ h1T){
  __shared__ float pooled[132];
  int g = blockIdx.x, t = threadIdx.x;
  if(t < 132){
    float s = 0.f;
    #pragma unroll
    for(int k=0;k<16;k++) s += pp[(size_t)(g*16 + k)*132 + t];
    int c = gend[g] - gstart[g]; if(c < 1) c = 1;
    pooled[t] = s/(float)c;
  }
  __syncthreads();
  #pragma unroll
  for(int r=0;r<4;r++){
    int o = r*256 + t;
    const float* wr = w + o*132;
    float acc = b[o];
    for(int k=0;k<132;k++) acc = fmaf(pooled[k], wr[k], acc);
    h1T[o*64+g] = fmaxf(acc, 0.f);
  }
}

__global__ __launch_bounds__(256) void k_fc2(const float* __restrict__ h1T, const float* __restrict__ w,
                                             const float* __restrict__ b, float* __restrict__ out){
  __shared__ float part[256];
  int o = blockIdx.x, t = threadIdx.x;
  int s = t >> 6, g = t & 63;
  const float* wr = w + o*1024 + s*256;
  const float* hp = h1T + (size_t)(s*256)*64 + g;
  float acc = 0.f;
  for(int k=0;k<256;k++) acc = fmaf(hp[k*64], wr[k], acc);
  part[t] = acc;
  __syncthreads();
  if(s == 0){
    float r = b[o] + part[g] + part[64+g] + part[128+g] + part[192+g];
    out[8192 + g*128 + o] = r;
  }
}

// ---------------- RNA branches ----------------
__device__ void sgather_body(const int* __restrict__ sci, const int* __restrict__ off,
                             const float* __restrict__ w, int V, int wstride,
                             int sstride, float* __restrict__ S,
                             int b, int q, int nsplit, int* loff, int* lci, int t){
  if(t <= V) loff[t] = off[b*(V+1) + t];
  __syncthreads();
  int vs = (V*q)/nsplit, ve = (V*(q+1))/nsplit;
  if(vs == ve) return;
  int p0 = loff[vs], p1 = loff[ve];
  for(int i=p0+t;i<p1;i+=256) lci[i-p0] = sci[b*3000 + i];
  __syncthreads();
  int co = t >> 3, kk = t & 7;
  const float* wrow = w + co*wstride + kk;
  float* Srow = S + (size_t)b*32*sstride + co*sstride + kk;
  for(int v=vs;v<ve;v++){
    int j = loff[v] - p0, je = loff[v+1] - p0;
    float a0=0.f,a1=0.f,a2=0.f,a3=0.f,a4=0.f,a5=0.f,a6=0.f,a7=0.f;
    for(; j+8 <= je; j += 8){
      a0 += wrow[lci[j]];
      a1 += wrow[lci[j+1]];
      a2 += wrow[lci[j+2]];
      a3 += wrow[lci[j+3]];
      a4 += wrow[lci[j+4]];
      a5 += wrow[lci[j+5]];
      a6 += wrow[lci[j+6]];
      a7 += wrow[lci[j+7]];
    }
    for(; j<je; j++) a0 += wrow[lci[j]];
    Srow[v*8] = ((a0+a1)+(a2+a3)) + ((a4+a5)+(a6+a7));
  }
}

__global__ __launch_bounds__(256) void k_sgather(const int* __restrict__ sci1, const int* __restrict__ off1,
                                                 const float* __restrict__ w1, float* __restrict__ S1,
                                                 const int* __restrict__ sci2, const int* __restrict__ off2,
                                                 const float* __restrict__ w2, float* __restrict__ S2){
  __shared__ int loff[66];
  __shared__ int lci[3000];
  int b = blockIdx.x, q = blockIdx.y, t = threadIdx.x;
  if(q < 5) sgather_body(sci1, off1, w1, 5, 24000, 40, S1, b, q, 5, loff, lci, t);
  else      sgather_body(sci2, off2, w2, 65, 23984, 520, S2, b, q-5, 32, loff, lci, t);
}

__global__ __launch_bounds__(128) void k_y(const float* __restrict__ S1, const float* __restrict__ S2,
                                           const float* __restrict__ emb1, const float* __restrict__ emb2,
                                           const float* __restrict__ c1b, const float* __restrict__ c2b,
                                           float* __restrict__ ysum){
  __shared__ float em1[640];
  __shared__ float em2[8320];
  __shared__ float Sa[320];
  __shared__ float Sb[4160];
  int b = blockIdx.x, cg = blockIdx.y, t = threadIdx.x;
  for(int i=t;i<640;i+=128)  em1[i] = emb1[i];
  for(int i=t;i<8320;i+=128) em2[i] = emb2[i];
  for(int i=t;i<320;i+=128)  Sa[i] = S1[b*1280 + cg*320 + i];
  for(int i=t;i<4160;i+=128) Sb[i] = S2[(size_t)b*16640 + cg*4160 + i];
  __syncthreads();
  if(t >= 121) return;
  #pragma unroll
  for(int c8=0;c8<8;c8++){
    int co = cg*8 + c8;
    const float* sa = Sa + c8*40;
    float acc1 = c1b[co];
    #pragma unroll
    for(int v=0;v<5;v++)
      #pragma unroll
      for(int k=0;k<8;k++) acc1 = fmaf(sa[v*8+k], em1[v*128 + t + k], acc1);
    const float* sb = Sb + c8*520;
    float acc2 = c2b[co];
    for(int v=0;v<65;v++){
      #pragma unroll
      for(int k=0;k<8;k++) acc2 = fmaf(sb[v*8+k], em2[v*128 + t + k], acc2);
    }
    ysum[b*3872 + co*121 + t] = 0.5f*(acc1 + acc2);
  }
}

__global__ __launch_bounds__(256) void k_fcxr(const float* __restrict__ ysum, const float* __restrict__ fcw,
                                              const float* __restrict__ fcb, float* __restrict__ out){
  __shared__ float part[512];
  int bp = blockIdx.x, q = blockIdx.y, t = threadIdx.x;
  int b0 = bp*2;
  int ol = t >> 3;
  int o  = q*32 + ol;
  int slice = t & 7;
  const float4* ys0 = (const float4*)(ysum + b0*3872) + slice*121;
  const float4* ys1 = (const float4*)(ysum + (b0+1)*3872) + slice*121;
  const float4* wr  = (const float4*)(fcw + (size_t)o*3872) + slice*121;
  float acc0 = 0.f, acc1 = 0.f;
  for(int k=0;k<121;k++){
    float4 w4 = wr[k];
    float4 y0 = ys0[k], y1 = ys1[k];
    acc0 += y0.x*w4.x + y0.y*w4.y + y0.z*w4.z + y0.w*w4.w;
    acc1 += y1.x*w4.x + y1.y*w4.y + y1.z*w4.z + y1.w*w4.w;
  }
  part[t] = acc0;
  part[256+t] = acc1;
  __syncthreads();
  if(slice == 0){
    float s0 = fcb[o], s1 = fcb[o];
    #pragma unroll
    for(int i=0;i<8;i++){ s0 += part[ol*8 + i]; s1 += part[256 + ol*8 + i]; }
    out[b0*128 + o] = s0;
    out[(b0+1)*128 + o] = s1;
  }
}

extern "C" void kernel_launch(void* const* d_in, const int* in_sizes, int n_in,
                              void* d_out, int out_size, void* d_ws, size_t ws_size,
                              hipStream_t stream){
  const int*   g_rna = (const int*)  d_in[0];
  const int*   l_rna = (const int*)  d_in[1];
  const float* pro_x = (const float*)d_in[2];
  const int*   eidx  = (const int*)  d_in[3];
  const float* pro_w = (const float*)d_in[4];
  const int*   batch = (const int*)  d_in[5];
  const float* emb1  = (const float*)d_in[6];
  const float* emb2  = (const float*)d_in[7];
  const float* c1w   = (const float*)d_in[8];
  const float* c1b   = (const float*)d_in[9];
  const float* c2w   = (const float*)d_in[10];
  const float* c2b   = (const float*)d_in[11];
  const float* fcxw  = (const float*)d_in[12];
  const float* fcxb  = (const float*)d_in[13];
  const float* gcnw  = (const float*)d_in[14];
  const float* gcnb  = (const float*)d_in[15];
  const float* bnm   = (const float*)d_in[16];
  const float* bnv   = (const float*)d_in[17];
  const float* bnw   = (const float*)d_in[18];
  const float* bnb   = (const float*)d_in[19];
  const float* gwl   = (const float*)d_in[20];
  const float* gwr   = (const float*)d_in[21];
  const float* gatt  = (const float*)d_in[22];
  const float* gatb  = (const float*)d_in[23];
  const float* f1w   = (const float*)d_in[24];
  const float* f1b   = (const float*)d_in[25];
  const float* f2w   = (const float*)d_in[26];
  const float* f2b_  = (const float*)d_in[27];
  float* out = (float*)d_out;

  char* ws = (char*)d_ws;
  size_t off = 0;
  auto A = [&](size_t n)->char*{ char* p = ws + off; off = (off + n + 255) & ~(size_t)255; return p; };
  u64*   pk     = (u64*)  A((size_t)N_NODES*8);
  int*   fill   = (int*)  A((size_t)N_NODES*4);
  int*   bcnt   = (int*)  A((size_t)NBUCK*4);
  int*   gstart = (int*)  A(64*4);
  int*   gend   = (int*)  A(64*4);
  size_t zero_bytes = off;
  int*   rowptr = (int*)  A((size_t)(N_NODES+1)*4);
  int*   bsum   = (int*)  A(196*4);
  int*   bbase  = (int*)  A(196*4);
  uint2* s_srcw = (uint2*)A((size_t)N_EDGES*8);
  u32*   hb     = (u32*)  A((size_t)N_NODES*17*4);
  float* xp1    = (float*)A((size_t)N_NODES*36*4);
  u32*   xlb    = (u32*)  A((size_t)N_NODES*72*4);
  float* xr     = (float*)A((size_t)N_NODES*132*4);
  float* xp2    = (float*)A((size_t)N_NODES*132*4);
  float* pp     = (float*)A((size_t)64*16*132*4);
  float* h1T    = (float*)A(1024*64*4);
  float* S1     = (float*)A((size_t)64*1280*4);
  float* S2     = (float*)A((size_t)64*16640*4);
  float* ysum   = (float*)A((size_t)64*3872*4);
  int*   sci1   = (int*)  A((size_t)64*3000*4);
  int*   off1   = (int*)  A((size_t)64*8*4);
  int*   sci2   = (int*)  A((size_t)64*3000*4);
  int*   off2   = (int*)  A((size_t)64*66*4);
  (void)ws_size; (void)in_sizes; (void)n_in; (void)out_size;

  // ebuf (12.8 MB, uint2 records) aliases xr (26.4 MB): dead until k_gatlin,
  // and the CSR build completes (stream-ordered) before k_gatlin writes xr.
  uint2* ebuf = (uint2*)xr;

  hipMemsetAsync(ws, 0, zero_bytes, stream);

  // fused input-only work: edge histogram + GCN linear + graph bounds + RNA buckets
  k_pre    <<<3645, 256, 0, stream>>>(eidx, pro_w, pk, pro_x, gcnw, hb,
                                      g_rna, l_rna, sci1, off1, sci2, off2,
                                      batch, gstart, gend);
  // protein CSR build
  k_scan1  <<<196, 256, 0, stream>>>(pk, rowptr, bsum);
  k_scan2  <<<1, 256, 0, stream>>>(bsum, bbase, rowptr);
  k_scan3  <<<196, 256, 0, stream>>>(rowptr, bbase);
  k_bin    <<<NBLKBIN, 256, 0, stream>>>(eidx, pro_w, pk, rowptr, fill, bcnt, ebuf, s_srcw);
  k_place  <<<NBUCK, 256, 0, stream>>>(bcnt, ebuf, rowptr, s_srcw);
  // protein GNN
  k_gcn    <<<12500, 256, 0, stream>>>(hb, rowptr, s_srcw, pk, gcnb, bnm, bnv, bnw, bnb, xp1);
  k_gatlin <<<782, 320, 0, stream>>>(xp1, gwl, gwr, gatt, xlb, xr);
  k_gat    <<<N_NODES, 128, 0, stream>>>(rowptr, (const u32*)s_srcw, xlb, xr, gatt, gatb, xp2);
  k_poolp  <<<dim3(64,16), 128, 0, stream>>>(xp2, gstart, gend, pp);
  k_pfc1   <<<64, 256, 0, stream>>>(pp, gstart, gend, f1w, f1b, h1T);
  k_fc2    <<<128, 256, 0, stream>>>(h1T, f2w, f2b_, out);

  // RNA branches
  k_sgather<<<dim3(64,37), 256, 0, stream>>>(sci1, off1, c1w, S1, sci2, off2, c2w, S2);
  k_y      <<<dim3(64,4), 128, 0, stream>>>(S1, S2, emb1, emb2, c1b, c2b, ysum);
  k_fcxr   <<<dim3(32,4), 256, 0, stream>>>(ysum, fcxw, fcxb, out);
}